// Round 16
// baseline (68.131 us; speedup 1.0000x reference)
//
#include <hip/hip_runtime.h>
#include <hip/hip_bf16.h>
#include <stdint.h>

#define BB    4
#define NQ    8192
#define NS    4096
#define FDIM  256
#define KNN   8
#define NT    512                // 8 waves; wave w owns tiles [16w,16w+16)
#define QPB   32                 // queries per block (one 32-col MFMA B set)
#define CAP   128                // candidate capacity (E=32, sigma~10 -> ~10 sigma)
#define MARGIN 0.0035f           // > 2x bf16-split error bound (~1.1e-3)
#define NTILES 128               // NS/32 total 32-sensor tiles
#define TPW   16                 // tiles per wave
#define SAMPT 4                  // sampled tiles per wave (1024 pooled samples)

typedef unsigned long long u64;
typedef __attribute__((ext_vector_type(8)))  short bf16x8;   // 8 bf16 (4 VGPR)
typedef __attribute__((ext_vector_type(16))) float f32x16;   // 32x32 C/D

__device__ __forceinline__ float med3(float a, float b, float c) {
    return __builtin_amdgcn_fmed3f(a, b, c);
}
__device__ __forceinline__ unsigned short f2bf(float v) {
    __hip_bfloat16 h = __float2bfloat16(v);
    return *reinterpret_cast<unsigned short*>(&h);
}
__device__ __forceinline__ float bf2f(unsigned short u) {
    __hip_bfloat16 h;
    *reinterpret_cast<unsigned short*>(&h) = u;
    return __bfloat162float(h);
}
// min of 16 (tree; clang fuses fminf pairs to v_min3 where possible)
__device__ __forceinline__ float min16(const f32x16& d) {
    const float m0 = fminf(fminf(d[0],  d[1]),  fminf(d[2],  d[3]));
    const float m1 = fminf(fminf(d[4],  d[5]),  fminf(d[6],  d[7]));
    const float m2 = fminf(fminf(d[8],  d[9]),  fminf(d[10], d[11]));
    const float m3 = fminf(fminf(d[12], d[13]), fminf(d[14], d[15]));
    return fminf(fminf(m0, m1), fminf(m2, m3));
}

// ---------------- d_ws layout ----------------
// tbl  : [NS][16] bf16 @ 0       (128 KB)  K=16 vectors (11 slots used)
// tblf : [NS] float4  @ 131072   (64 KB)   (-2x,-2y,-2z,s^2) f32 for refine
#define WS_TBLF  131072
#define WS_NEED  196608

// ============ build: bf16 K-vector table + f32 refine table ============
// k: 0:s2_hi 1:s2_lo 2:mx_hi 3:mx_lo 4:mx_hi 5:my_hi 6:my_lo 7:my_hi
//    8:mz_hi 9:mz_lo 10:mz_hi 11..15:0        (m* = -2*coord)
__global__ __launch_bounds__(256) void build_tbl(const float* __restrict__ sc,
                                                 unsigned short* __restrict__ tbl,
                                                 float4* __restrict__ tblf) {
    const int s = blockIdx.x * 256 + threadIdx.x;
    if (s >= NS) return;
    const float sx = sc[3*s], sy = sc[3*s+1], sz = sc[3*s+2];
    const float s2 = __fmaf_rn(sx, sx, __fmaf_rn(sy, sy, __fmul_rn(sz, sz)));
    const float mx = -2.0f*sx, my = -2.0f*sy, mz = -2.0f*sz;
    unsigned short e[16];
    #pragma unroll
    for (int j = 0; j < 16; ++j) e[j] = 0;
    unsigned short h, l;
    h = f2bf(s2); l = f2bf(s2 - bf2f(h)); e[0] = h; e[1] = l;
    h = f2bf(mx); l = f2bf(mx - bf2f(h)); e[2] = h; e[3] = l; e[4]  = h;
    h = f2bf(my); l = f2bf(my - bf2f(h)); e[5] = h; e[6] = l; e[7]  = h;
    h = f2bf(mz); l = f2bf(mz - bf2f(h)); e[8] = h; e[9] = l; e[10] = h;
    #pragma unroll
    for (int j = 0; j < 16; ++j) tbl[s * 16 + j] = e[j];
    tblf[s] = make_float4(mx, my, mz, s2);
}

// ===== main: pooled-sample threshold -> 32x32 MFMA sweep -> parallel exact refine ====
__global__ __launch_bounds__(NT, 8) void knn_mfma(
    const float* __restrict__ qc, const float* __restrict__ sf,
    const unsigned short* __restrict__ tbl, const float4* __restrict__ tblf,
    float* __restrict__ out)
{
    __shared__ unsigned short s_qvec[QPB][16];   // query K-vectors (1 KB)
    __shared__ float4 s_q[QPB];                  // qx,qy,qz,q2 (f32, refine)
    __shared__ float  s_samp[8][KNN][QPB + 1];   // padded: pool reads 2-way max
    __shared__ float  s_thrq[QPB];               // pooled threshold (+MARGIN)
    __shared__ int    s_cnt[QPB];
    __shared__ int    s_cand[QPB][CAP];          // 16 KB
    __shared__ int    s_idx[QPB][KNN];
    __shared__ float  s_w[QPB][KNN];

    const int tid = threadIdx.x;

    // XCD swizzle: batch b -> XCD pair {2b,2b+1}; bijective over 1024 blocks.
    const int p   = blockIdx.x;
    const int b   = (p >> 1) & 3;
    const int sub = ((p >> 3) << 1) | (p & 1);   // 0..255
    const int q0  = b * NQ + sub * QPB;

    // ---- stage query K-vectors + f32 coords ----
    if (tid < QPB) {
        const float* qp = qc + (size_t)(q0 + tid) * 3;
        const float qx = qp[0], qy = qp[1], qz = qp[2];
        const float q2 = __fmaf_rn(qx, qx, __fmaf_rn(qy, qy, __fmul_rn(qz, qz)));
        s_q[tid] = make_float4(qx, qy, qz, q2);
        #pragma unroll
        for (int j = 11; j < 16; ++j) s_qvec[tid][j] = 0;
        const unsigned short one = f2bf(1.0f);
        unsigned short h, l;
        s_qvec[tid][0] = one; s_qvec[tid][1] = one;
        h = f2bf(qx); l = f2bf(qx - bf2f(h));
        s_qvec[tid][2] = h; s_qvec[tid][3] = h; s_qvec[tid][4]  = l;
        h = f2bf(qy); l = f2bf(qy - bf2f(h));
        s_qvec[tid][5] = h; s_qvec[tid][6] = h; s_qvec[tid][7]  = l;
        h = f2bf(qz); l = f2bf(qz - bf2f(h));
        s_qvec[tid][8] = h; s_qvec[tid][9] = h; s_qvec[tid][10] = l;
        s_cnt[tid] = 0;
    }
    __syncthreads();

    const int wid  = tid >> 6;        // wave 0..7 -> tiles [wid*16, wid*16+16)
    const int lane = tid & 63;
    const int ln31 = lane & 31;       // A row within tile / B query col
    const int kc   = lane >> 5;       // k-chunk 0..1 (A/B k = 8*kc + j)
    const int t0   = wid * TPW;

    // B fragment: col = lane&31 (query), k = 8*(lane>>5)+j  [r13-verified]
    const bf16x8 bfrag = *reinterpret_cast<const bf16x8*>(&s_qvec[ln31][kc * 8]);
    const f32x16 zero = {};

    // A fragment source: row = lane&31 (sensor in tile), k = 8*(lane>>5)+j
    const unsigned short* abase = tbl + ((size_t)ln31 * 16 + kc * 8);

    // ---- pass S: top-8 over 4 sampled tiles (128 sensors/query/wave; 1024 pooled) ----
    float kd[KNN];
    #pragma unroll
    for (int j = 0; j < KNN; ++j) kd[j] = 3.4e38f;

    #pragma unroll
    for (int ts = 0; ts < SAMPT; ++ts) {
        const int t = t0 + ts * (TPW / SAMPT);
        const bf16x8 a = *reinterpret_cast<const bf16x8*>(abase + (size_t)t * 512);
        const f32x16 d = __builtin_amdgcn_mfma_f32_32x32x16_bf16(a, bfrag, zero, 0, 0, 0);
        if (min16(d) < kd[KNN-1]) {          // wave-cheap skip; insert no-op otherwise
            #pragma unroll
            for (int r = 0; r < 16; ++r) {
                const float x = d[r];
                if (x < kd[KNN-1]) {
                    const float nk0 = fminf(kd[0], x);
                    #pragma unroll
                    for (int j = KNN - 1; j >= 1; --j) kd[j] = med3(kd[j-1], kd[j], x);
                    kd[0] = nk0;
                }
            }
        }
    }

    // ---- prefetch pass-C tile 0 (read-only table; legal across barriers) ----
    bf16x8 aC = *reinterpret_cast<const bf16x8*>(abase + (size_t)t0 * 512);

    // ---- tournament over the 2 lanes holding this query (xor 32): record top-8 ----
    float smp[KNN];
    #pragma unroll
    for (int r = 0; r < KNN; ++r) {
        float m = fminf(kd[0], __shfl_xor(kd[0], 32, 64));
        const bool pop = (kd[0] == m);   // tie over-pop only RAISES values (safe)
        #pragma unroll
        for (int j = 0; j < KNN - 1; ++j) kd[j] = pop ? kd[j+1] : kd[j];
        kd[KNN-1] = pop ? 3.4e38f : kd[KNN-1];
        smp[r] = m;
    }
    if (lane < 32) {
        #pragma unroll
        for (int r = 0; r < KNN; ++r) s_samp[wid][r][ln31] = smp[r];  // stride-1
    }
    __syncthreads();

    // ---- parallel pool: subgroup (wid,sg) pools query qr = wid*4+sg ----
    // 64 sample values; lane li holds 4 sorted; 8-round 16-lane pop-tournament
    // -> pooled sample-8th (exact: global-top-8 samples lie in per-wave top-8s).
    {
        const int sg = lane >> 4;
        const int li = lane & 15;
        const int qr = wid * 4 + sg;
        const int v0 = li * 4;
        const float x0 = s_samp[(v0+0) >> 3][(v0+0) & 7][qr];
        const float x1 = s_samp[(v0+1) >> 3][(v0+1) & 7][qr];
        const float x2 = s_samp[(v0+2) >> 3][(v0+2) & 7][qr];
        const float x3 = s_samp[(v0+3) >> 3][(v0+3) & 7][qr];
        // sort-4 network (ascending)
        const float a0 = fminf(x0, x1), a1 = fmaxf(x0, x1);
        const float a2 = fminf(x2, x3), a3 = fmaxf(x2, x3);
        const float b0 = fminf(a0, a2), b2 = fmaxf(a0, a2);
        const float b1 = fminf(a1, a3), b3 = fmaxf(a1, a3);
        float l0 = b0, l1 = fminf(b1, b2), l2 = fmaxf(b1, b2), l3 = b3;
        float m = 3.4e38f;
        #pragma unroll
        for (int r = 0; r < KNN; ++r) {
            m = l0;
            m = fminf(m, __shfl_xor(m, 1, 64));
            m = fminf(m, __shfl_xor(m, 2, 64));
            m = fminf(m, __shfl_xor(m, 4, 64));
            m = fminf(m, __shfl_xor(m, 8, 64));
            const bool pop = (l0 == m);
            l0 = pop ? l1 : l0;
            l1 = pop ? l2 : l1;
            l2 = pop ? l3 : l2;
            l3 = pop ? 3.4e38f : l3;
        }
        if (li == 0) s_thrq[qr] = m + MARGIN;   // superset threshold (proof as r8)
    }
    __syncthreads();

    const float thr_eff = s_thrq[ln31];

    // ---- pass C: sweep 16 tiles (prefetched A, min-tree skip, batched atomic) ----
    {
        const unsigned short* ap = abase + (size_t)t0 * 512;
        bf16x8 a = aC;
        int sid0 = t0 * 32 + 4 * kc;     // + (r&3) + 8*(r>>2) per element
        #pragma unroll 2
        for (int tt = 0; tt < TPW; ++tt) {
            bf16x8 an = a;
            if (tt + 1 < TPW) {
                ap += 512;
                an = *reinterpret_cast<const bf16x8*>(ap);
            }
            const f32x16 d = __builtin_amdgcn_mfma_f32_32x32x16_bf16(a, bfrag, zero, 0, 0, 0);
            if (min16(d) <= thr_eff) {   // rare path only (~12.5% of lane-tiles)
                bool h[16];
                int n = 0;
                #pragma unroll
                for (int r = 0; r < 16; ++r) { h[r] = d[r] <= thr_eff; n += (int)h[r]; }
                int pos = atomicAdd(&s_cnt[ln31], n);   // one atomic per hit lane-tile
                #pragma unroll
                for (int r = 0; r < 16; ++r) {
                    if (h[r]) {
                        if (pos < CAP) s_cand[ln31][pos] = sid0 + (r & 3) + 8 * (r >> 2);
                        ++pos;
                    }
                }
            }
            a = an;
            sid0 += 32;
        }
    }
    __syncthreads();

    // ---- parallel exact refine: wave wid -> queries wid*4..+3 ----
    // 16 lanes per query split candidates; per-lane sorted u64 top-8;
    // 16-lane u64 pop-tournament -> exact top-8 (keys unique -> one pop).
    {
        const int sg = lane >> 4;            // subgroup 0..3
        const int li = lane & 15;            // lane within subgroup
        const int qr = wid * 4 + sg;         // query refined by this subgroup (0..31)
        const int cnt0 = s_cnt[qr];
        const float qx = s_q[qr].x, qy = s_q[qr].y, qz = s_q[qr].z, q2 = s_q[qr].w;

        u64 kb[KNN];
        #pragma unroll
        for (int j = 0; j < KNN; ++j) kb[j] = ~0ull;

        if (cnt0 <= CAP) {
            for (int i = li; i < cnt0; i += 16) {
                const int sid = s_cand[qr][i];
                const float4 m = tblf[sid];
                const float x  = __fmaf_rn(qx, m.x,
                                 __fmaf_rn(qy, m.y, __fmaf_rn(qz, m.z, m.w)));
                const float d2 = fmaxf(__fadd_rn(x, q2), 0.0f);
                u64 cur = ((u64)__float_as_uint(d2) << 32) | (unsigned)sid;
                #pragma unroll
                for (int j = 0; j < KNN; ++j) {
                    const u64 lo = kb[j] < cur ? kb[j] : cur;
                    const u64 hi = kb[j] < cur ? cur : kb[j];
                    kb[j] = lo; cur = hi;
                }
            }
        } else {
            // safety net (~10 sigma): exact full scan, split over 16 lanes
            for (int sid = li; sid < NS; sid += 16) {
                const float4 m = tblf[sid];
                const float x  = __fmaf_rn(qx, m.x,
                                 __fmaf_rn(qy, m.y, __fmaf_rn(qz, m.z, m.w)));
                const float d2 = fmaxf(__fadd_rn(x, q2), 0.0f);
                u64 cur = ((u64)__float_as_uint(d2) << 32) | (unsigned)sid;
                #pragma unroll
                for (int j = 0; j < KNN; ++j) {
                    const u64 lo = kb[j] < cur ? kb[j] : cur;
                    const u64 hi = kb[j] < cur ? cur : kb[j];
                    kb[j] = lo; cur = hi;
                }
            }
        }

        u64 sel = ~0ull;
        #pragma unroll
        for (int r = 0; r < KNN; ++r) {
            u64 v = kb[0];
            #pragma unroll
            for (int m = 1; m <= 8; m <<= 1) {
                const u64 o = __shfl_xor(v, m, 64);   // stays within 16-lane group
                v = o < v ? o : v;
            }
            const bool pop = (kb[0] == v);
            #pragma unroll
            for (int j = 0; j < KNN - 1; ++j) kb[j] = pop ? kb[j+1] : kb[j];
            kb[KNN-1] = pop ? ~0ull : kb[KNN-1];
            if (li == r) sel = v;
        }

        // weights on lanes 0..7 of each subgroup (xor 1,2,4 stays within 0..7)
        const float d2v = __uint_as_float((unsigned)(sel >> 32));
        const int   idx = (int)(unsigned)(sel & 0xFFFFFFFFu);
        const float w   = 1.0f / (sqrtf(d2v) + 1e-8f);
        float ws = w;
        ws += __shfl_xor(ws, 1, 64);
        ws += __shfl_xor(ws, 2, 64);
        ws += __shfl_xor(ws, 4, 64);
        if (li < KNN) {
            s_idx[qr][li] = idx;
            s_w[qr][li]   = w / ws;
        }
    }
    __syncthreads();

    // ---- gather: wave wid -> queries wid*4..+3; 64 lanes x float4 ----
    const float* fb = sf + (size_t)b * NS * FDIM;
    #pragma unroll 2
    for (int jq = 0; jq < QPB / 8; ++jq) {
        const int ql = wid * (QPB / 8) + jq;
        float4 acc = {0.f, 0.f, 0.f, 0.f};
        #pragma unroll
        for (int kk = 0; kk < KNN; ++kk) {
            const int   sid = s_idx[ql][kk];
            const float wk  = s_w[ql][kk];
            const float4 v = ((const float4*)(fb + (size_t)sid * FDIM))[lane];
            acc.x += wk * v.x; acc.y += wk * v.y;
            acc.z += wk * v.z; acc.w += wk * v.w;
        }
        ((float4*)(out + (size_t)(q0 + ql) * FDIM))[lane] = acc;
    }
}

// ================= fallback (round-6 kernel) if workspace too small =================
#define FG    16
#define FQL   2
#define FNT   512
#define FGRP  (FNT / FG)
#define FQPB  (FGRP * FQL)
#define FSCAN (NS / FG)
#define FCAP  16

#define FKEYX(m, qq) __fmaf_rn(fqx[qq], (m).x, \
                     __fmaf_rn(fqy[qq], (m).y, \
                     __fmaf_rn(fqz[qq], (m).z, (m).w)))

__global__ __launch_bounds__(FNT, 4) void idw_fallback(
    const float* __restrict__ qc, const float* __restrict__ sc,
    const float* __restrict__ sf, float* __restrict__ out)
{
    __shared__ float4 s_m[NS];
    __shared__ u64    s_items[FQPB * FCAP];
    __shared__ int    s_cnt[FQPB];
    __shared__ int    s_idx[FQPB * KNN];
    __shared__ float  s_w[FQPB * KNN];

    const int tid = threadIdx.x;
    const int p   = blockIdx.x;
    const int b   = (p >> 1) & 3;
    const int sub = ((p >> 3) << 1) | (p & 1);
    const int q0  = b * NQ + sub * FQPB;

    for (int s = tid; s < NS; s += FNT) {
        const float sx = sc[3*s+0], sy = sc[3*s+1], sz = sc[3*s+2];
        const float s2 = __fmaf_rn(sx, sx, __fmaf_rn(sy, sy, __fmul_rn(sz, sz)));
        s_m[s] = make_float4(-2.0f*sx, -2.0f*sy, -2.0f*sz, s2);
    }
    if (tid < FQPB) s_cnt[tid] = 0;
    __syncthreads();

    const int g = tid >> 4, l = tid & 15;
    float fqx[FQL], fqy[FQL], fqz[FQL], fq2[FQL];
    #pragma unroll
    for (int qq = 0; qq < FQL; ++qq) {
        const float* qp = qc + (size_t)(q0 + g * FQL + qq) * 3;
        fqx[qq] = qp[0]; fqy[qq] = qp[1]; fqz[qq] = qp[2];
        fq2[qq] = __fmaf_rn(fqx[qq], fqx[qq],
                  __fmaf_rn(fqy[qq], fqy[qq], __fmul_rn(fqz[qq], fqz[qq])));
    }

    float kd[FQL][KNN];
    #pragma unroll
    for (int qq = 0; qq < FQL; ++qq)
        #pragma unroll
        for (int j = 0; j < KNN; ++j) kd[qq][j] = 3.4e38f;

    #pragma unroll 2
    for (int t = 0; t < FSCAN; ++t) {
        const float4 m = s_m[t * FG + l];
        #pragma unroll
        for (int qq = 0; qq < FQL; ++qq) {
            const float x = FKEYX(m, qq);
            const float nk0 = fminf(kd[qq][0], x);
            #pragma unroll
            for (int j = KNN - 1; j >= 1; --j)
                kd[qq][j] = med3(kd[qq][j-1], kd[qq][j], x);
            kd[qq][0] = nk0;
        }
    }

    float thr[FQL];
    #pragma unroll
    for (int qq = 0; qq < FQL; ++qq) {
        float thv = 3.4e38f;
        #pragma unroll
        for (int r = 0; r < KNN; ++r) {
            float m = kd[qq][0];
            m = fminf(m, __shfl_xor(m, 1, 64));
            m = fminf(m, __shfl_xor(m, 2, 64));
            m = fminf(m, __shfl_xor(m, 4, 64));
            m = fminf(m, __shfl_xor(m, 8, 64));
            const bool pop = (kd[qq][0] == m);
            #pragma unroll
            for (int j = 0; j < KNN - 1; ++j) kd[qq][j] = pop ? kd[qq][j+1] : kd[qq][j];
            kd[qq][KNN-1] = pop ? 3.4e38f : kd[qq][KNN-1];
            thv = m;
        }
        thr[qq] = thv;
    }

    #pragma unroll 2
    for (int t = 0; t < FSCAN; ++t) {
        const int s = t * FG + l;
        const float4 m = s_m[s];
        #pragma unroll
        for (int qq = 0; qq < FQL; ++qq) {
            const float x = FKEYX(m, qq);
            if (x <= thr[qq]) {
                const float dc = fmaxf(__fadd_rn(x, fq2[qq]), 0.0f);
                const u64 key = ((u64)__float_as_uint(dc) << 32) | (unsigned)s;
                const int qid = g * FQL + qq;
                const int pos = atomicAdd(&s_cnt[qid], 1);
                if (pos < FCAP) s_items[qid * FCAP + pos] = key;
            }
        }
    }
    __syncthreads();

    if (l < FQL) {
        const int qid = g * FQL + l;
        int cnt = s_cnt[qid];
        if (cnt > KNN) {
            cnt = cnt < FCAP ? cnt : FCAP;
            u64 best[KNN];
            #pragma unroll
            for (int j = 0; j < KNN; ++j) best[j] = ~0ull;
            for (int i = 0; i < cnt; ++i) {
                u64 cur = s_items[qid * FCAP + i];
                #pragma unroll
                for (int j = 0; j < KNN; ++j) {
                    const u64 lo = best[j] < cur ? best[j] : cur;
                    const u64 hi = best[j] < cur ? cur : best[j];
                    best[j] = lo; cur = hi;
                }
            }
            #pragma unroll
            for (int j = 0; j < KNN; ++j) s_items[qid * FCAP + j] = best[j];
        }
    }
    __syncthreads();

    {
        const int qq  = l >> 3;
        const int k   = l & 7;
        const int qid = g * FQL + qq;
        const u64 key = s_items[qid * FCAP + k];
        const float d2v = __uint_as_float((unsigned)(key >> 32));
        const int   idx = (int)(unsigned)(key & 0xFFFFFFFFu);
        const float w   = 1.0f / (sqrtf(d2v) + 1e-8f);
        float ws = w;
        ws += __shfl_xor(ws, 1, 64);
        ws += __shfl_xor(ws, 2, 64);
        ws += __shfl_xor(ws, 4, 64);
        s_idx[qid * KNN + k] = idx;
        s_w  [qid * KNN + k] = w / ws;
    }
    __syncthreads();

    const int wave = tid >> 6, lane = tid & 63;
    const float* fb = sf + (size_t)b * NS * FDIM;
    #pragma unroll 1
    for (int j = 0; j < FQPB / 8; ++j) {
        const int ql = wave * (FQPB / 8) + j;
        float4 acc = {0.f, 0.f, 0.f, 0.f};
        #pragma unroll
        for (int kk = 0; kk < KNN; ++kk) {
            const int   sid = s_idx[ql * KNN + kk];
            const float wk  = s_w  [ql * KNN + kk];
            const float4 v = ((const float4*)(fb + (size_t)sid * FDIM))[lane];
            acc.x += wk * v.x; acc.y += wk * v.y;
            acc.z += wk * v.z; acc.w += wk * v.w;
        }
        ((float4*)(out + (size_t)(q0 + ql) * FDIM))[lane] = acc;
    }
}

extern "C" void kernel_launch(void* const* d_in, const int* in_sizes, int n_in,
                              void* d_out, int out_size, void* d_ws, size_t ws_size,
                              hipStream_t stream) {
    const float* qc = (const float*)d_in[0];   // query_coords  (4,8192,3)
    const float* sc = (const float*)d_in[1];   // sensor_coords (4096,3)
    const float* sf = (const float*)d_in[2];   // sensor_features (4,4096,256)
    float* out = (float*)d_out;                // (4,8192,256)

    if (ws_size >= (size_t)WS_NEED) {
        unsigned short* tbl  = (unsigned short*)d_ws;
        float4*         tblf = (float4*)((char*)d_ws + WS_TBLF);
        build_tbl<<<NS / 256, 256, 0, stream>>>(sc, tbl, tblf);
        knn_mfma<<<(BB * NQ) / QPB, NT, 0, stream>>>(qc, sf, tbl, tblf, out);
    } else {
        idw_fallback<<<(BB * NQ) / FQPB, FNT, 0, stream>>>(qc, sc, sf, out);
    }
}

// Round 17
// 57.756 us; speedup vs baseline: 1.1796x; 1.1796x over previous
//
#include <hip/hip_runtime.h>
#include <hip/hip_bf16.h>
#include <stdint.h>

#define BB    4
#define NQ    8192
#define NS    4096
#define FDIM  256
#define KNN   8
#define NT    512                // 8 waves; wave w owns tiles [16w,16w+16)
#define QPB   32                 // queries per block (one 32-col MFMA B set)
#define CAP   128                // candidate capacity (E=32, sigma~10 -> ~10 sigma)
#define MARGIN 0.0035f           // > 2x bf16-split error bound (~1.1e-3)
#define NTILES 128               // NS/32 total 32-sensor tiles
#define TPW   16                 // tiles per wave
#define SAMPT 4                  // sampled tiles per wave (1024 pooled samples)

typedef unsigned long long u64;
typedef __attribute__((ext_vector_type(8)))  short bf16x8;   // 8 bf16 (4 VGPR)
typedef __attribute__((ext_vector_type(16))) float f32x16;   // 32x32 C/D

__device__ __forceinline__ float med3(float a, float b, float c) {
    return __builtin_amdgcn_fmed3f(a, b, c);
}
__device__ __forceinline__ unsigned short f2bf(float v) {
    __hip_bfloat16 h = __float2bfloat16(v);
    return *reinterpret_cast<unsigned short*>(&h);
}
__device__ __forceinline__ float bf2f(unsigned short u) {
    __hip_bfloat16 h;
    *reinterpret_cast<unsigned short*>(&h) = u;
    return __bfloat162float(h);
}

// ---------------- d_ws layout ----------------
// tbl  : [NS][16] bf16 @ 0       (128 KB)  K=16 vectors (11 slots used)
// tblf : [NS] float4  @ 131072   (64 KB)   (-2x,-2y,-2z,s^2) f32 for refine
#define WS_TBLF  131072
#define WS_NEED  196608

// ============ build: bf16 K-vector table + f32 refine table ============
// k: 0:s2_hi 1:s2_lo 2:mx_hi 3:mx_lo 4:mx_hi 5:my_hi 6:my_lo 7:my_hi
//    8:mz_hi 9:mz_lo 10:mz_hi 11..15:0        (m* = -2*coord)
__global__ __launch_bounds__(256) void build_tbl(const float* __restrict__ sc,
                                                 unsigned short* __restrict__ tbl,
                                                 float4* __restrict__ tblf) {
    const int s = blockIdx.x * 256 + threadIdx.x;
    if (s >= NS) return;
    const float sx = sc[3*s], sy = sc[3*s+1], sz = sc[3*s+2];
    const float s2 = __fmaf_rn(sx, sx, __fmaf_rn(sy, sy, __fmul_rn(sz, sz)));
    const float mx = -2.0f*sx, my = -2.0f*sy, mz = -2.0f*sz;
    unsigned short e[16];
    #pragma unroll
    for (int j = 0; j < 16; ++j) e[j] = 0;
    unsigned short h, l;
    h = f2bf(s2); l = f2bf(s2 - bf2f(h)); e[0] = h; e[1] = l;
    h = f2bf(mx); l = f2bf(mx - bf2f(h)); e[2] = h; e[3] = l; e[4]  = h;
    h = f2bf(my); l = f2bf(my - bf2f(h)); e[5] = h; e[6] = l; e[7]  = h;
    h = f2bf(mz); l = f2bf(mz - bf2f(h)); e[8] = h; e[9] = l; e[10] = h;
    #pragma unroll
    for (int j = 0; j < 16; ++j) tbl[s * 16 + j] = e[j];
    tblf[s] = make_float4(mx, my, mz, s2);
}

// ===== main: pooled-sample threshold -> 32x32 MFMA sweep -> parallel exact refine ====
__global__ __launch_bounds__(NT, 8) void knn_mfma(
    const float* __restrict__ qc, const float* __restrict__ sf,
    const unsigned short* __restrict__ tbl, const float4* __restrict__ tblf,
    float* __restrict__ out)
{
    __shared__ unsigned short s_qvec[QPB][16];   // query K-vectors (1 KB)
    __shared__ float4 s_q[QPB];                  // qx,qy,qz,q2 (f32, refine)
    __shared__ float  s_samp[8][KNN][QPB + 1];   // padded: pool reads 2-way max
    __shared__ float  s_thrq[QPB];               // pooled threshold (+MARGIN)
    __shared__ int    s_cnt[QPB];
    __shared__ int    s_cand[QPB][CAP];          // 16 KB
    __shared__ int    s_idx[QPB][KNN];
    __shared__ float  s_w[QPB][KNN];

    const int tid = threadIdx.x;

    // XCD swizzle: batch b -> XCD pair {2b,2b+1}; bijective over 1024 blocks.
    const int p   = blockIdx.x;
    const int b   = (p >> 1) & 3;
    const int sub = ((p >> 3) << 1) | (p & 1);   // 0..255
    const int q0  = b * NQ + sub * QPB;

    // ---- stage query K-vectors + f32 coords ----
    if (tid < QPB) {
        const float* qp = qc + (size_t)(q0 + tid) * 3;
        const float qx = qp[0], qy = qp[1], qz = qp[2];
        const float q2 = __fmaf_rn(qx, qx, __fmaf_rn(qy, qy, __fmul_rn(qz, qz)));
        s_q[tid] = make_float4(qx, qy, qz, q2);
        #pragma unroll
        for (int j = 11; j < 16; ++j) s_qvec[tid][j] = 0;
        const unsigned short one = f2bf(1.0f);
        unsigned short h, l;
        s_qvec[tid][0] = one; s_qvec[tid][1] = one;
        h = f2bf(qx); l = f2bf(qx - bf2f(h));
        s_qvec[tid][2] = h; s_qvec[tid][3] = h; s_qvec[tid][4]  = l;
        h = f2bf(qy); l = f2bf(qy - bf2f(h));
        s_qvec[tid][5] = h; s_qvec[tid][6] = h; s_qvec[tid][7]  = l;
        h = f2bf(qz); l = f2bf(qz - bf2f(h));
        s_qvec[tid][8] = h; s_qvec[tid][9] = h; s_qvec[tid][10] = l;
        s_cnt[tid] = 0;
    }
    __syncthreads();

    const int wid  = tid >> 6;        // wave 0..7 -> tiles [wid*16, wid*16+16)
    const int lane = tid & 63;
    const int ln31 = lane & 31;       // A row within tile / B query col
    const int kc   = lane >> 5;       // k-chunk 0..1 (A/B k = 8*kc + j)
    const int t0   = wid * TPW;

    // B fragment: col = lane&31 (query), k = 8*(lane>>5)+j  [r13-verified]
    const bf16x8 bfrag = *reinterpret_cast<const bf16x8*>(&s_qvec[ln31][kc * 8]);
    const f32x16 zero = {};

    // A fragment source: row = lane&31 (sensor in tile), k = 8*(lane>>5)+j
    const unsigned short* abase = tbl + ((size_t)ln31 * 16 + kc * 8);

    // ---- pass S: top-8 over 4 sampled tiles (unconditional med3 insert;
    //      per-element guards are wave-useless: P(any-lane inserts) ~= 1) ----
    float kd[KNN];
    #pragma unroll
    for (int j = 0; j < KNN; ++j) kd[j] = 3.4e38f;

    #pragma unroll
    for (int ts = 0; ts < SAMPT; ++ts) {
        const int t = t0 + ts * (TPW / SAMPT);
        const bf16x8 a = *reinterpret_cast<const bf16x8*>(abase + (size_t)t * 512);
        const f32x16 d = __builtin_amdgcn_mfma_f32_32x32x16_bf16(a, bfrag, zero, 0, 0, 0);
        #pragma unroll
        for (int r = 0; r < 16; ++r) {
            const float x = d[r];
            const float nk0 = fminf(kd[0], x);
            #pragma unroll
            for (int j = KNN - 1; j >= 1; --j) kd[j] = med3(kd[j-1], kd[j], x);
            kd[0] = nk0;
        }
    }

    // ---- prefetch pass-C tile 0 (read-only table; legal across barriers) ----
    bf16x8 aC = *reinterpret_cast<const bf16x8*>(abase + (size_t)t0 * 512);

    // ---- tournament over the 2 lanes holding this query (xor 32): record top-8 ----
    float smp[KNN];
    #pragma unroll
    for (int r = 0; r < KNN; ++r) {
        float m = fminf(kd[0], __shfl_xor(kd[0], 32, 64));
        const bool pop = (kd[0] == m);   // tie over-pop only RAISES values (safe)
        #pragma unroll
        for (int j = 0; j < KNN - 1; ++j) kd[j] = pop ? kd[j+1] : kd[j];
        kd[KNN-1] = pop ? 3.4e38f : kd[KNN-1];
        smp[r] = m;
    }
    if (lane < 32) {
        #pragma unroll
        for (int r = 0; r < KNN; ++r) s_samp[wid][r][ln31] = smp[r];  // stride-1
    }
    __syncthreads();

    // ---- parallel pool: subgroup (wid,sg) pools query qr = wid*4+sg ----
    // 64 sample values; lane li holds 4 sorted; 8-round 16-lane pop-tournament
    // -> pooled sample-8th (exact: global-top-8 samples lie in per-wave top-8s).
    {
        const int sg = lane >> 4;
        const int li = lane & 15;
        const int qr = wid * 4 + sg;
        const int v0 = li * 4;
        const float x0 = s_samp[(v0+0) >> 3][(v0+0) & 7][qr];
        const float x1 = s_samp[(v0+1) >> 3][(v0+1) & 7][qr];
        const float x2 = s_samp[(v0+2) >> 3][(v0+2) & 7][qr];
        const float x3 = s_samp[(v0+3) >> 3][(v0+3) & 7][qr];
        // sort-4 network (ascending)
        const float a0 = fminf(x0, x1), a1 = fmaxf(x0, x1);
        const float a2 = fminf(x2, x3), a3 = fmaxf(x2, x3);
        const float b0 = fminf(a0, a2), b2 = fmaxf(a0, a2);
        const float b1 = fminf(a1, a3), b3 = fmaxf(a1, a3);
        float l0 = b0, l1 = fminf(b1, b2), l2 = fmaxf(b1, b2), l3 = b3;
        float m = 3.4e38f;
        #pragma unroll
        for (int r = 0; r < KNN; ++r) {
            m = l0;
            m = fminf(m, __shfl_xor(m, 1, 64));
            m = fminf(m, __shfl_xor(m, 2, 64));
            m = fminf(m, __shfl_xor(m, 4, 64));
            m = fminf(m, __shfl_xor(m, 8, 64));
            const bool pop = (l0 == m);
            l0 = pop ? l1 : l0;
            l1 = pop ? l2 : l1;
            l2 = pop ? l3 : l2;
            l3 = pop ? 3.4e38f : l3;
        }
        if (li == 0) s_thrq[qr] = m + MARGIN;   // superset threshold (proof as r8)
    }
    __syncthreads();

    const float thr_eff = s_thrq[ln31];

    // ---- pass C: sweep 16 tiles (prefetched A; mask+popc+ffs compaction) ----
    {
        const unsigned short* ap = abase + (size_t)t0 * 512;
        bf16x8 a = aC;
        int sid0 = t0 * 32 + 4 * kc;     // + (r&3) + 8*(r>>2) per element
        #pragma unroll 2
        for (int tt = 0; tt < TPW; ++tt) {
            bf16x8 an = a;
            if (tt + 1 < TPW) {
                ap += 512;
                an = *reinterpret_cast<const bf16x8*>(ap);
            }
            const f32x16 d = __builtin_amdgcn_mfma_f32_32x32x16_bf16(a, bfrag, zero, 0, 0, 0);
            unsigned m = 0;
            #pragma unroll
            for (int r = 0; r < 16; ++r) m |= (d[r] <= thr_eff) ? (1u << r) : 0u;
            if (m) {
                int pos = atomicAdd(&s_cnt[ln31], __popc(m));
                while (m) {                      // iterations = per-lane hits (~1-3)
                    const int r = __ffs(m) - 1;
                    m &= m - 1;
                    if (pos < CAP) s_cand[ln31][pos] = sid0 + (r & 3) + 8 * (r >> 2);
                    ++pos;
                }
            }
            a = an;
            sid0 += 32;
        }
    }
    __syncthreads();

    // ---- parallel exact refine: wave wid -> queries wid*4..+3 ----
    // 16 lanes per query split candidates; per-lane sorted u64 top-8;
    // 16-lane u64 pop-tournament -> exact top-8 (keys unique -> one pop).
    {
        const int sg = lane >> 4;            // subgroup 0..3
        const int li = lane & 15;            // lane within subgroup
        const int qr = wid * 4 + sg;         // query refined by this subgroup (0..31)
        const int cnt0 = s_cnt[qr];
        const float qx = s_q[qr].x, qy = s_q[qr].y, qz = s_q[qr].z, q2 = s_q[qr].w;

        u64 kb[KNN];
        #pragma unroll
        for (int j = 0; j < KNN; ++j) kb[j] = ~0ull;

        if (cnt0 <= CAP) {
            for (int i = li; i < cnt0; i += 16) {
                const int sid = s_cand[qr][i];
                const float4 m = tblf[sid];
                const float x  = __fmaf_rn(qx, m.x,
                                 __fmaf_rn(qy, m.y, __fmaf_rn(qz, m.z, m.w)));
                const float d2 = fmaxf(__fadd_rn(x, q2), 0.0f);
                u64 cur = ((u64)__float_as_uint(d2) << 32) | (unsigned)sid;
                #pragma unroll
                for (int j = 0; j < KNN; ++j) {
                    const u64 lo = kb[j] < cur ? kb[j] : cur;
                    const u64 hi = kb[j] < cur ? cur : kb[j];
                    kb[j] = lo; cur = hi;
                }
            }
        } else {
            // safety net (~10 sigma): exact full scan, split over 16 lanes
            for (int sid = li; sid < NS; sid += 16) {
                const float4 m = tblf[sid];
                const float x  = __fmaf_rn(qx, m.x,
                                 __fmaf_rn(qy, m.y, __fmaf_rn(qz, m.z, m.w)));
                const float d2 = fmaxf(__fadd_rn(x, q2), 0.0f);
                u64 cur = ((u64)__float_as_uint(d2) << 32) | (unsigned)sid;
                #pragma unroll
                for (int j = 0; j < KNN; ++j) {
                    const u64 lo = kb[j] < cur ? kb[j] : cur;
                    const u64 hi = kb[j] < cur ? cur : kb[j];
                    kb[j] = lo; cur = hi;
                }
            }
        }

        u64 sel = ~0ull;
        #pragma unroll
        for (int r = 0; r < KNN; ++r) {
            u64 v = kb[0];
            #pragma unroll
            for (int m = 1; m <= 8; m <<= 1) {
                const u64 o = __shfl_xor(v, m, 64);   // stays within 16-lane group
                v = o < v ? o : v;
            }
            const bool pop = (kb[0] == v);
            #pragma unroll
            for (int j = 0; j < KNN - 1; ++j) kb[j] = pop ? kb[j+1] : kb[j];
            kb[KNN-1] = pop ? ~0ull : kb[KNN-1];
            if (li == r) sel = v;
        }

        // weights on lanes 0..7 of each subgroup (xor 1,2,4 stays within 0..7)
        const float d2v = __uint_as_float((unsigned)(sel >> 32));
        const int   idx = (int)(unsigned)(sel & 0xFFFFFFFFu);
        const float w   = 1.0f / (sqrtf(d2v) + 1e-8f);
        float ws = w;
        ws += __shfl_xor(ws, 1, 64);
        ws += __shfl_xor(ws, 2, 64);
        ws += __shfl_xor(ws, 4, 64);
        if (li < KNN) {
            s_idx[qr][li] = idx;
            s_w[qr][li]   = w / ws;
        }
    }
    __syncthreads();

    // ---- gather: wave wid -> queries wid*4..+3; 64 lanes x float4 ----
    const float* fb = sf + (size_t)b * NS * FDIM;
    #pragma unroll 2
    for (int jq = 0; jq < QPB / 8; ++jq) {
        const int ql = wid * (QPB / 8) + jq;
        float4 acc = {0.f, 0.f, 0.f, 0.f};
        #pragma unroll
        for (int kk = 0; kk < KNN; ++kk) {
            const int   sid = s_idx[ql][kk];
            const float wk  = s_w[ql][kk];
            const float4 v = ((const float4*)(fb + (size_t)sid * FDIM))[lane];
            acc.x += wk * v.x; acc.y += wk * v.y;
            acc.z += wk * v.z; acc.w += wk * v.w;
        }
        ((float4*)(out + (size_t)(q0 + ql) * FDIM))[lane] = acc;
    }
}

// ================= fallback (round-6 kernel) if workspace too small =================
#define FG    16
#define FQL   2
#define FNT   512
#define FGRP  (FNT / FG)
#define FQPB  (FGRP * FQL)
#define FSCAN (NS / FG)
#define FCAP  16

#define FKEYX(m, qq) __fmaf_rn(fqx[qq], (m).x, \
                     __fmaf_rn(fqy[qq], (m).y, \
                     __fmaf_rn(fqz[qq], (m).z, (m).w)))

__global__ __launch_bounds__(FNT, 4) void idw_fallback(
    const float* __restrict__ qc, const float* __restrict__ sc,
    const float* __restrict__ sf, float* __restrict__ out)
{
    __shared__ float4 s_m[NS];
    __shared__ u64    s_items[FQPB * FCAP];
    __shared__ int    s_cnt[FQPB];
    __shared__ int    s_idx[FQPB * KNN];
    __shared__ float  s_w[FQPB * KNN];

    const int tid = threadIdx.x;
    const int p   = blockIdx.x;
    const int b   = (p >> 1) & 3;
    const int sub = ((p >> 3) << 1) | (p & 1);
    const int q0  = b * NQ + sub * FQPB;

    for (int s = tid; s < NS; s += FNT) {
        const float sx = sc[3*s+0], sy = sc[3*s+1], sz = sc[3*s+2];
        const float s2 = __fmaf_rn(sx, sx, __fmaf_rn(sy, sy, __fmul_rn(sz, sz)));
        s_m[s] = make_float4(-2.0f*sx, -2.0f*sy, -2.0f*sz, s2);
    }
    if (tid < FQPB) s_cnt[tid] = 0;
    __syncthreads();

    const int g = tid >> 4, l = tid & 15;
    float fqx[FQL], fqy[FQL], fqz[FQL], fq2[FQL];
    #pragma unroll
    for (int qq = 0; qq < FQL; ++qq) {
        const float* qp = qc + (size_t)(q0 + g * FQL + qq) * 3;
        fqx[qq] = qp[0]; fqy[qq] = qp[1]; fqz[qq] = qp[2];
        fq2[qq] = __fmaf_rn(fqx[qq], fqx[qq],
                  __fmaf_rn(fqy[qq], fqy[qq], __fmul_rn(fqz[qq], fqz[qq])));
    }

    float kd[FQL][KNN];
    #pragma unroll
    for (int qq = 0; qq < FQL; ++qq)
        #pragma unroll
        for (int j = 0; j < KNN; ++j) kd[qq][j] = 3.4e38f;

    #pragma unroll 2
    for (int t = 0; t < FSCAN; ++t) {
        const float4 m = s_m[t * FG + l];
        #pragma unroll
        for (int qq = 0; qq < FQL; ++qq) {
            const float x = FKEYX(m, qq);
            const float nk0 = fminf(kd[qq][0], x);
            #pragma unroll
            for (int j = KNN - 1; j >= 1; --j)
                kd[qq][j] = med3(kd[qq][j-1], kd[qq][j], x);
            kd[qq][0] = nk0;
        }
    }

    float thr[FQL];
    #pragma unroll
    for (int qq = 0; qq < FQL; ++qq) {
        float thv = 3.4e38f;
        #pragma unroll
        for (int r = 0; r < KNN; ++r) {
            float m = kd[qq][0];
            m = fminf(m, __shfl_xor(m, 1, 64));
            m = fminf(m, __shfl_xor(m, 2, 64));
            m = fminf(m, __shfl_xor(m, 4, 64));
            m = fminf(m, __shfl_xor(m, 8, 64));
            const bool pop = (kd[qq][0] == m);
            #pragma unroll
            for (int j = 0; j < KNN - 1; ++j) kd[qq][j] = pop ? kd[qq][j+1] : kd[qq][j];
            kd[qq][KNN-1] = pop ? 3.4e38f : kd[qq][KNN-1];
            thv = m;
        }
        thr[qq] = thv;
    }

    #pragma unroll 2
    for (int t = 0; t < FSCAN; ++t) {
        const int s = t * FG + l;
        const float4 m = s_m[s];
        #pragma unroll
        for (int qq = 0; qq < FQL; ++qq) {
            const float x = FKEYX(m, qq);
            if (x <= thr[qq]) {
                const float dc = fmaxf(__fadd_rn(x, fq2[qq]), 0.0f);
                const u64 key = ((u64)__float_as_uint(dc) << 32) | (unsigned)s;
                const int qid = g * FQL + qq;
                const int pos = atomicAdd(&s_cnt[qid], 1);
                if (pos < FCAP) s_items[qid * FCAP + pos] = key;
            }
        }
    }
    __syncthreads();

    if (l < FQL) {
        const int qid = g * FQL + l;
        int cnt = s_cnt[qid];
        if (cnt > KNN) {
            cnt = cnt < FCAP ? cnt : FCAP;
            u64 best[KNN];
            #pragma unroll
            for (int j = 0; j < KNN; ++j) best[j] = ~0ull;
            for (int i = 0; i < cnt; ++i) {
                u64 cur = s_items[qid * FCAP + i];
                #pragma unroll
                for (int j = 0; j < KNN; ++j) {
                    const u64 lo = best[j] < cur ? best[j] : cur;
                    const u64 hi = best[j] < cur ? cur : best[j];
                    best[j] = lo; cur = hi;
                }
            }
            #pragma unroll
            for (int j = 0; j < KNN; ++j) s_items[qid * FCAP + j] = best[j];
        }
    }
    __syncthreads();

    {
        const int qq  = l >> 3;
        const int k   = l & 7;
        const int qid = g * FQL + qq;
        const u64 key = s_items[qid * FCAP + k];
        const float d2v = __uint_as_float((unsigned)(key >> 32));
        const int   idx = (int)(unsigned)(key & 0xFFFFFFFFu);
        const float w   = 1.0f / (sqrtf(d2v) + 1e-8f);
        float ws = w;
        ws += __shfl_xor(ws, 1, 64);
        ws += __shfl_xor(ws, 2, 64);
        ws += __shfl_xor(ws, 4, 64);
        s_idx[qid * KNN + k] = idx;
        s_w  [qid * KNN + k] = w / ws;
    }
    __syncthreads();

    const int wave = tid >> 6, lane = tid & 63;
    const float* fb = sf + (size_t)b * NS * FDIM;
    #pragma unroll 1
    for (int j = 0; j < FQPB / 8; ++j) {
        const int ql = wave * (FQPB / 8) + j;
        float4 acc = {0.f, 0.f, 0.f, 0.f};
        #pragma unroll
        for (int kk = 0; kk < KNN; ++kk) {
            const int   sid = s_idx[ql * KNN + kk];
            const float wk  = s_w  [ql * KNN + kk];
            const float4 v = ((const float4*)(fb + (size_t)sid * FDIM))[lane];
            acc.x += wk * v.x; acc.y += wk * v.y;
            acc.z += wk * v.z; acc.w += wk * v.w;
        }
        ((float4*)(out + (size_t)(q0 + ql) * FDIM))[lane] = acc;
    }
}

extern "C" void kernel_launch(void* const* d_in, const int* in_sizes, int n_in,
                              void* d_out, int out_size, void* d_ws, size_t ws_size,
                              hipStream_t stream) {
    const float* qc = (const float*)d_in[0];   // query_coords  (4,8192,3)
    const float* sc = (const float*)d_in[1];   // sensor_coords (4096,3)
    const float* sf = (const float*)d_in[2];   // sensor_features (4,4096,256)
    float* out = (float*)d_out;                // (4,8192,256)

    if (ws_size >= (size_t)WS_NEED) {
        unsigned short* tbl  = (unsigned short*)d_ws;
        float4*         tblf = (float4*)((char*)d_ws + WS_TBLF);
        build_tbl<<<NS / 256, 256, 0, stream>>>(sc, tbl, tblf);
        knn_mfma<<<(BB * NQ) / QPB, NT, 0, stream>>>(qc, sf, tbl, tblf, out);
    } else {
        idw_fallback<<<(BB * NQ) / FQPB, FNT, 0, stream>>>(qc, sc, sf, out);
    }
}

// Round 18
// 55.129 us; speedup vs baseline: 1.2359x; 1.0477x over previous
//
#include <hip/hip_runtime.h>
#include <hip/hip_bf16.h>
#include <stdint.h>

#define BB    4
#define NQ    8192
#define NS    4096
#define FDIM  256
#define KNN   8
#define NT    512                // 8 waves; wave w owns tiles [16w,16w+16)
#define QPB   32                 // queries per block (one 32-col MFMA B set)
#define CAP   128                // candidate capacity (E=32, sigma~10 -> ~10 sigma)
#define MARGIN 0.0035f           // > 2x bf16-split error bound (~1.1e-3)
#define TPW   16                 // tiles per wave
#define SAMPT 4                  // sampled tiles per wave (1024 pooled samples)

typedef unsigned long long u64;
typedef __attribute__((ext_vector_type(8)))  short bf16x8;   // 8 bf16 (4 VGPR)
typedef __attribute__((ext_vector_type(16))) float f32x16;   // 32x32 C/D

__device__ __forceinline__ float med3(float a, float b, float c) {
    return __builtin_amdgcn_fmed3f(a, b, c);
}
__device__ __forceinline__ unsigned short f2bf(float v) {
    __hip_bfloat16 h = __float2bfloat16(v);
    return *reinterpret_cast<unsigned short*>(&h);
}
__device__ __forceinline__ float bf2f(unsigned short u) {
    __hip_bfloat16 h;
    *reinterpret_cast<unsigned short*>(&h) = u;
    return __bfloat162float(h);
}

// ---------------- d_ws layout ----------------
// tbl  : [NS][16] bf16 @ 0       (128 KB)  K=16 vectors (11 slots used)
// tblf : [NS] float4  @ 131072   (64 KB)   (-2x,-2y,-2z,s^2) f32 for refine
#define WS_TBLF  131072
#define WS_NEED  196608

// ============ build: bf16 K-vector table + f32 refine table ============
// k: 0:s2_hi 1:s2_lo 2:mx_hi 3:mx_lo 4:mx_hi 5:my_hi 6:my_lo 7:my_hi
//    8:mz_hi 9:mz_lo 10:mz_hi 11..15:0        (m* = -2*coord)
__global__ __launch_bounds__(256) void build_tbl(const float* __restrict__ sc,
                                                 unsigned short* __restrict__ tbl,
                                                 float4* __restrict__ tblf) {
    const int s = blockIdx.x * 256 + threadIdx.x;
    if (s >= NS) return;
    const float sx = sc[3*s], sy = sc[3*s+1], sz = sc[3*s+2];
    const float s2 = __fmaf_rn(sx, sx, __fmaf_rn(sy, sy, __fmul_rn(sz, sz)));
    const float mx = -2.0f*sx, my = -2.0f*sy, mz = -2.0f*sz;
    unsigned short e[16];
    #pragma unroll
    for (int j = 0; j < 16; ++j) e[j] = 0;
    unsigned short h, l;
    h = f2bf(s2); l = f2bf(s2 - bf2f(h)); e[0] = h; e[1] = l;
    h = f2bf(mx); l = f2bf(mx - bf2f(h)); e[2] = h; e[3] = l; e[4]  = h;
    h = f2bf(my); l = f2bf(my - bf2f(h)); e[5] = h; e[6] = l; e[7]  = h;
    h = f2bf(mz); l = f2bf(mz - bf2f(h)); e[8] = h; e[9] = l; e[10] = h;
    #pragma unroll
    for (int j = 0; j < 16; ++j) tbl[s * 16 + j] = e[j];
    tblf[s] = make_float4(mx, my, mz, s2);
}

// ===== main: pooled-sample threshold -> 32x32 MFMA sweep -> parallel exact refine ====
__global__ __launch_bounds__(NT, 8) void knn_mfma(
    const float* __restrict__ qc, const float* __restrict__ sf,
    const unsigned short* __restrict__ tbl, const float4* __restrict__ tblf,
    float* __restrict__ out)
{
    __shared__ unsigned short s_qvec[QPB][16];   // query K-vectors (1 KB)
    __shared__ float4 s_q[QPB];                  // qx,qy,qz,q2 (f32, refine)
    __shared__ float  s_samp[8][8][QPB + 1];     // per-lane top-4s; padded reads
    __shared__ float  s_thrq[QPB];               // pooled threshold (+MARGIN)
    __shared__ int    s_cnt[QPB];
    __shared__ int    s_cand[QPB][CAP];          // 16 KB
    __shared__ int    s_idx[QPB][KNN];
    __shared__ float  s_w[QPB][KNN];

    const int tid = threadIdx.x;

    // XCD swizzle: batch b -> XCD pair {2b,2b+1}; bijective over 1024 blocks.
    const int p   = blockIdx.x;
    const int b   = (p >> 1) & 3;
    const int sub = ((p >> 3) << 1) | (p & 1);   // 0..255
    const int q0  = b * NQ + sub * QPB;

    // ---- stage query K-vectors + f32 coords ----
    if (tid < QPB) {
        const float* qp = qc + (size_t)(q0 + tid) * 3;
        const float qx = qp[0], qy = qp[1], qz = qp[2];
        const float q2 = __fmaf_rn(qx, qx, __fmaf_rn(qy, qy, __fmul_rn(qz, qz)));
        s_q[tid] = make_float4(qx, qy, qz, q2);
        #pragma unroll
        for (int j = 11; j < 16; ++j) s_qvec[tid][j] = 0;
        const unsigned short one = f2bf(1.0f);
        unsigned short h, l;
        s_qvec[tid][0] = one; s_qvec[tid][1] = one;
        h = f2bf(qx); l = f2bf(qx - bf2f(h));
        s_qvec[tid][2] = h; s_qvec[tid][3] = h; s_qvec[tid][4]  = l;
        h = f2bf(qy); l = f2bf(qy - bf2f(h));
        s_qvec[tid][5] = h; s_qvec[tid][6] = h; s_qvec[tid][7]  = l;
        h = f2bf(qz); l = f2bf(qz - bf2f(h));
        s_qvec[tid][8] = h; s_qvec[tid][9] = h; s_qvec[tid][10] = l;
        s_cnt[tid] = 0;
    }
    __syncthreads();

    const int wid  = tid >> 6;        // wave 0..7 -> tiles [wid*16, wid*16+16)
    const int lane = tid & 63;
    const int ln31 = lane & 31;       // A row within tile / B query col
    const int kc   = lane >> 5;       // k-chunk 0..1 (A/B k = 8*kc + j)
    const int t0   = wid * TPW;

    // B fragment: col = lane&31 (query), k = 8*(lane>>5)+j  [r13-verified]
    const bf16x8 bfrag = *reinterpret_cast<const bf16x8*>(&s_qvec[ln31][kc * 8]);
    const f32x16 zero = {};

    // A fragment source: row = lane&31 (sensor in tile), k = 8*(lane>>5)+j
    const unsigned short* abase = tbl + ((size_t)ln31 * 16 + kc * 8);

    // ---- pass S: per-lane TOP-4 over 4 sampled tiles (64 values/lane).
    // Recording only top-4/lane can only RAISE the pooled 8th (safe over-
    // threshold; P(lane holds >=5 of pooled top-8) ~ 1e-5). 5 ops/sample. ----
    float kd0 = 3.4e38f, kd1 = 3.4e38f, kd2 = 3.4e38f, kd3 = 3.4e38f;

    #pragma unroll
    for (int ts = 0; ts < SAMPT; ++ts) {
        const int t = t0 + ts * (TPW / SAMPT);
        const bf16x8 a = *reinterpret_cast<const bf16x8*>(abase + (size_t)t * 512);
        const f32x16 d = __builtin_amdgcn_mfma_f32_32x32x16_bf16(a, bfrag, zero, 0, 0, 0);
        #pragma unroll
        for (int r = 0; r < 16; ++r) {
            const float x = d[r];
            const float nk0 = fminf(kd0, x);
            kd3 = med3(kd2, kd3, x);
            kd2 = med3(kd1, kd2, x);
            kd1 = med3(kd0, kd1, x);
            kd0 = nk0;
        }
    }

    // ---- prefetch pass-C tile 0 (read-only table; legal across barriers) ----
    bf16x8 aC = *reinterpret_cast<const bf16x8*>(abase + (size_t)t0 * 512);

    // ---- record: each lane writes its sorted top-4 (slot = kc*4+j), stride-1 ----
    s_samp[wid][kc * 4 + 0][ln31] = kd0;
    s_samp[wid][kc * 4 + 1][ln31] = kd1;
    s_samp[wid][kc * 4 + 2][ln31] = kd2;
    s_samp[wid][kc * 4 + 3][ln31] = kd3;
    __syncthreads();

    // ---- parallel pool: subgroup (wid,sg) pools query qr = wid*4+sg ----
    // 64 recorded values; lane li holds 4 sorted; 8-round 16-lane pop-tournament
    // -> pooled sample-8th (tie over-pop only raises thr; refine is exact anyway).
    {
        const int sg = lane >> 4;
        const int li = lane & 15;
        const int qr = wid * 4 + sg;
        const int v0 = li * 4;
        const float x0 = s_samp[(v0+0) >> 3][(v0+0) & 7][qr];
        const float x1 = s_samp[(v0+1) >> 3][(v0+1) & 7][qr];
        const float x2 = s_samp[(v0+2) >> 3][(v0+2) & 7][qr];
        const float x3 = s_samp[(v0+3) >> 3][(v0+3) & 7][qr];
        // sort-4 network (ascending)
        const float a0 = fminf(x0, x1), a1 = fmaxf(x0, x1);
        const float a2 = fminf(x2, x3), a3 = fmaxf(x2, x3);
        const float b0 = fminf(a0, a2), b2 = fmaxf(a0, a2);
        const float b1 = fminf(a1, a3), b3 = fmaxf(a1, a3);
        float l0 = b0, l1 = fminf(b1, b2), l2 = fmaxf(b1, b2), l3 = b3;
        float m = 3.4e38f;
        #pragma unroll
        for (int r = 0; r < KNN; ++r) {
            m = l0;
            m = fminf(m, __shfl_xor(m, 1, 64));
            m = fminf(m, __shfl_xor(m, 2, 64));
            m = fminf(m, __shfl_xor(m, 4, 64));
            m = fminf(m, __shfl_xor(m, 8, 64));
            const bool pop = (l0 == m);
            l0 = pop ? l1 : l0;
            l1 = pop ? l2 : l1;
            l2 = pop ? l3 : l2;
            l3 = pop ? 3.4e38f : l3;
        }
        if (li == 0) s_thrq[qr] = m + MARGIN;   // superset threshold (proof as r8)
    }
    __syncthreads();

    const float thr_eff = s_thrq[ln31];

    // ---- pass C: sweep 16 tiles (prefetched A; mask+popc+ffs compaction) ----
    {
        const unsigned short* ap = abase + (size_t)t0 * 512;
        bf16x8 a = aC;
        int sid0 = t0 * 32 + 4 * kc;     // + (r&3) + 8*(r>>2) per element
        #pragma unroll 4
        for (int tt = 0; tt < TPW; ++tt) {
            bf16x8 an = a;
            if (tt + 1 < TPW) {
                ap += 512;
                an = *reinterpret_cast<const bf16x8*>(ap);
            }
            const f32x16 d = __builtin_amdgcn_mfma_f32_32x32x16_bf16(a, bfrag, zero, 0, 0, 0);
            unsigned m = 0;
            #pragma unroll
            for (int r = 0; r < 16; ++r) m |= (d[r] <= thr_eff) ? (1u << r) : 0u;
            if (m) {
                int pos = atomicAdd(&s_cnt[ln31], __popc(m));
                while (m) {                      // iterations = per-lane hits (~1-3)
                    const int r = __ffs(m) - 1;
                    m &= m - 1;
                    if (pos < CAP) s_cand[ln31][pos] = sid0 + (r & 3) + 8 * (r >> 2);
                    ++pos;
                }
            }
            a = an;
            sid0 += 32;
        }
    }
    __syncthreads();

    // ---- parallel exact refine: wave wid -> queries wid*4..+3 ----
    // 16 lanes per query split candidates; per-lane sorted u64 top-8;
    // 16-lane u64 pop-tournament -> exact top-8 (keys unique -> one pop).
    {
        const int sg = lane >> 4;            // subgroup 0..3
        const int li = lane & 15;            // lane within subgroup
        const int qr = wid * 4 + sg;         // query refined by this subgroup (0..31)
        const int cnt0 = s_cnt[qr];
        const float qx = s_q[qr].x, qy = s_q[qr].y, qz = s_q[qr].z, q2 = s_q[qr].w;

        u64 kb[KNN];
        #pragma unroll
        for (int j = 0; j < KNN; ++j) kb[j] = ~0ull;

        if (cnt0 <= CAP) {
            for (int i = li; i < cnt0; i += 16) {
                const int sid = s_cand[qr][i];
                const float4 m = tblf[sid];
                const float x  = __fmaf_rn(qx, m.x,
                                 __fmaf_rn(qy, m.y, __fmaf_rn(qz, m.z, m.w)));
                const float d2 = fmaxf(__fadd_rn(x, q2), 0.0f);
                u64 cur = ((u64)__float_as_uint(d2) << 32) | (unsigned)sid;
                #pragma unroll
                for (int j = 0; j < KNN; ++j) {
                    const u64 lo = kb[j] < cur ? kb[j] : cur;
                    const u64 hi = kb[j] < cur ? cur : kb[j];
                    kb[j] = lo; cur = hi;
                }
            }
        } else {
            // safety net (~10 sigma): exact full scan, split over 16 lanes
            for (int sid = li; sid < NS; sid += 16) {
                const float4 m = tblf[sid];
                const float x  = __fmaf_rn(qx, m.x,
                                 __fmaf_rn(qy, m.y, __fmaf_rn(qz, m.z, m.w)));
                const float d2 = fmaxf(__fadd_rn(x, q2), 0.0f);
                u64 cur = ((u64)__float_as_uint(d2) << 32) | (unsigned)sid;
                #pragma unroll
                for (int j = 0; j < KNN; ++j) {
                    const u64 lo = kb[j] < cur ? kb[j] : cur;
                    const u64 hi = kb[j] < cur ? cur : kb[j];
                    kb[j] = lo; cur = hi;
                }
            }
        }

        u64 sel = ~0ull;
        #pragma unroll
        for (int r = 0; r < KNN; ++r) {
            u64 v = kb[0];
            #pragma unroll
            for (int m = 1; m <= 8; m <<= 1) {
                const u64 o = __shfl_xor(v, m, 64);   // stays within 16-lane group
                v = o < v ? o : v;
            }
            const bool pop = (kb[0] == v);
            #pragma unroll
            for (int j = 0; j < KNN - 1; ++j) kb[j] = pop ? kb[j+1] : kb[j];
            kb[KNN-1] = pop ? ~0ull : kb[KNN-1];
            if (li == r) sel = v;
        }

        // weights on lanes 0..7 of each subgroup (xor 1,2,4 stays within 0..7)
        const float d2v = __uint_as_float((unsigned)(sel >> 32));
        const int   idx = (int)(unsigned)(sel & 0xFFFFFFFFu);
        const float w   = 1.0f / (sqrtf(d2v) + 1e-8f);
        float ws = w;
        ws += __shfl_xor(ws, 1, 64);
        ws += __shfl_xor(ws, 2, 64);
        ws += __shfl_xor(ws, 4, 64);
        if (li < KNN) {
            s_idx[qr][li] = idx;
            s_w[qr][li]   = w / ws;
        }
    }
    __syncthreads();

    // ---- gather: wave wid -> queries wid*4..+3; 64 lanes x float4 ----
    const float* fb = sf + (size_t)b * NS * FDIM;
    #pragma unroll 2
    for (int jq = 0; jq < QPB / 8; ++jq) {
        const int ql = wid * (QPB / 8) + jq;
        float4 acc = {0.f, 0.f, 0.f, 0.f};
        #pragma unroll
        for (int kk = 0; kk < KNN; ++kk) {
            const int   sid = s_idx[ql][kk];
            const float wk  = s_w[ql][kk];
            const float4 v = ((const float4*)(fb + (size_t)sid * FDIM))[lane];
            acc.x += wk * v.x; acc.y += wk * v.y;
            acc.z += wk * v.z; acc.w += wk * v.w;
        }
        ((float4*)(out + (size_t)(q0 + ql) * FDIM))[lane] = acc;
    }
}

// ================= fallback (round-6 kernel) if workspace too small =================
#define FG    16
#define FQL   2
#define FNT   512
#define FGRP  (FNT / FG)
#define FQPB  (FGRP * FQL)
#define FSCAN (NS / FG)
#define FCAP  16

#define FKEYX(m, qq) __fmaf_rn(fqx[qq], (m).x, \
                     __fmaf_rn(fqy[qq], (m).y, \
                     __fmaf_rn(fqz[qq], (m).z, (m).w)))

__global__ __launch_bounds__(FNT, 4) void idw_fallback(
    const float* __restrict__ qc, const float* __restrict__ sc,
    const float* __restrict__ sf, float* __restrict__ out)
{
    __shared__ float4 s_m[NS];
    __shared__ u64    s_items[FQPB * FCAP];
    __shared__ int    s_cnt[FQPB];
    __shared__ int    s_idx[FQPB * KNN];
    __shared__ float  s_w[FQPB * KNN];

    const int tid = threadIdx.x;
    const int p   = blockIdx.x;
    const int b   = (p >> 1) & 3;
    const int sub = ((p >> 3) << 1) | (p & 1);
    const int q0  = b * NQ + sub * FQPB;

    for (int s = tid; s < NS; s += FNT) {
        const float sx = sc[3*s+0], sy = sc[3*s+1], sz = sc[3*s+2];
        const float s2 = __fmaf_rn(sx, sx, __fmaf_rn(sy, sy, __fmul_rn(sz, sz)));
        s_m[s] = make_float4(-2.0f*sx, -2.0f*sy, -2.0f*sz, s2);
    }
    if (tid < FQPB) s_cnt[tid] = 0;
    __syncthreads();

    const int g = tid >> 4, l = tid & 15;
    float fqx[FQL], fqy[FQL], fqz[FQL], fq2[FQL];
    #pragma unroll
    for (int qq = 0; qq < FQL; ++qq) {
        const float* qp = qc + (size_t)(q0 + g * FQL + qq) * 3;
        fqx[qq] = qp[0]; fqy[qq] = qp[1]; fqz[qq] = qp[2];
        fq2[qq] = __fmaf_rn(fqx[qq], fqx[qq],
                  __fmaf_rn(fqy[qq], fqy[qq], __fmul_rn(fqz[qq], fqz[qq])));
    }

    float kd[FQL][KNN];
    #pragma unroll
    for (int qq = 0; qq < FQL; ++qq)
        #pragma unroll
        for (int j = 0; j < KNN; ++j) kd[qq][j] = 3.4e38f;

    #pragma unroll 2
    for (int t = 0; t < FSCAN; ++t) {
        const float4 m = s_m[t * FG + l];
        #pragma unroll
        for (int qq = 0; qq < FQL; ++qq) {
            const float x = FKEYX(m, qq);
            const float nk0 = fminf(kd[qq][0], x);
            #pragma unroll
            for (int j = KNN - 1; j >= 1; --j)
                kd[qq][j] = med3(kd[qq][j-1], kd[qq][j], x);
            kd[qq][0] = nk0;
        }
    }

    float thr[FQL];
    #pragma unroll
    for (int qq = 0; qq < FQL; ++qq) {
        float thv = 3.4e38f;
        #pragma unroll
        for (int r = 0; r < KNN; ++r) {
            float m = kd[qq][0];
            m = fminf(m, __shfl_xor(m, 1, 64));
            m = fminf(m, __shfl_xor(m, 2, 64));
            m = fminf(m, __shfl_xor(m, 4, 64));
            m = fminf(m, __shfl_xor(m, 8, 64));
            const bool pop = (kd[qq][0] == m);
            #pragma unroll
            for (int j = 0; j < KNN - 1; ++j) kd[qq][j] = pop ? kd[qq][j+1] : kd[qq][j];
            kd[qq][KNN-1] = pop ? 3.4e38f : kd[qq][KNN-1];
            thv = m;
        }
        thr[qq] = thv;
    }

    #pragma unroll 2
    for (int t = 0; t < FSCAN; ++t) {
        const int s = t * FG + l;
        const float4 m = s_m[s];
        #pragma unroll
        for (int qq = 0; qq < FQL; ++qq) {
            const float x = FKEYX(m, qq);
            if (x <= thr[qq]) {
                const float dc = fmaxf(__fadd_rn(x, fq2[qq]), 0.0f);
                const u64 key = ((u64)__float_as_uint(dc) << 32) | (unsigned)s;
                const int qid = g * FQL + qq;
                const int pos = atomicAdd(&s_cnt[qid], 1);
                if (pos < FCAP) s_items[qid * FCAP + pos] = key;
            }
        }
    }
    __syncthreads();

    if (l < FQL) {
        const int qid = g * FQL + l;
        int cnt = s_cnt[qid];
        if (cnt > KNN) {
            cnt = cnt < FCAP ? cnt : FCAP;
            u64 best[KNN];
            #pragma unroll
            for (int j = 0; j < KNN; ++j) best[j] = ~0ull;
            for (int i = 0; i < cnt; ++i) {
                u64 cur = s_items[qid * FCAP + i];
                #pragma unroll
                for (int j = 0; j < KNN; ++j) {
                    const u64 lo = best[j] < cur ? best[j] : cur;
                    const u64 hi = best[j] < cur ? cur : best[j];
                    best[j] = lo; cur = hi;
                }
            }
            #pragma unroll
            for (int j = 0; j < KNN; ++j) s_items[qid * FCAP + j] = best[j];
        }
    }
    __syncthreads();

    {
        const int qq  = l >> 3;
        const int k   = l & 7;
        const int qid = g * FQL + qq;
        const u64 key = s_items[qid * FCAP + k];
        const float d2v = __uint_as_float((unsigned)(key >> 32));
        const int   idx = (int)(unsigned)(key & 0xFFFFFFFFu);
        const float w   = 1.0f / (sqrtf(d2v) + 1e-8f);
        float ws = w;
        ws += __shfl_xor(ws, 1, 64);
        ws += __shfl_xor(ws, 2, 64);
        ws += __shfl_xor(ws, 4, 64);
        s_idx[qid * KNN + k] = idx;
        s_w  [qid * KNN + k] = w / ws;
    }
    __syncthreads();

    const int wave = tid >> 6, lane = tid & 63;
    const float* fb = sf + (size_t)b * NS * FDIM;
    #pragma unroll 1
    for (int j = 0; j < FQPB / 8; ++j) {
        const int ql = wave * (FQPB / 8) + j;
        float4 acc = {0.f, 0.f, 0.f, 0.f};
        #pragma unroll
        for (int kk = 0; kk < KNN; ++kk) {
            const int   sid = s_idx[ql * KNN + kk];
            const float wk  = s_w  [ql * KNN + kk];
            const float4 v = ((const float4*)(fb + (size_t)sid * FDIM))[lane];
            acc.x += wk * v.x; acc.y += wk * v.y;
            acc.z += wk * v.z; acc.w += wk * v.w;
        }
        ((float4*)(out + (size_t)(q0 + ql) * FDIM))[lane] = acc;
    }
}

extern "C" void kernel_launch(void* const* d_in, const int* in_sizes, int n_in,
                              void* d_out, int out_size, void* d_ws, size_t ws_size,
                              hipStream_t stream) {
    const float* qc = (const float*)d_in[0];   // query_coords  (4,8192,3)
    const float* sc = (const float*)d_in[1];   // sensor_coords (4096,3)
    const float* sf = (const float*)d_in[2];   // sensor_features (4,4096,256)
    float* out = (float*)d_out;                // (4,8192,256)

    if (ws_size >= (size_t)WS_NEED) {
        unsigned short* tbl  = (unsigned short*)d_ws;
        float4*         tblf = (float4*)((char*)d_ws + WS_TBLF);
        build_tbl<<<NS / 256, 256, 0, stream>>>(sc, tbl, tblf);
        knn_mfma<<<(BB * NQ) / QPB, NT, 0, stream>>>(qc, sf, tbl, tblf, out);
    } else {
        idw_fallback<<<(BB * NQ) / FQPB, FNT, 0, stream>>>(qc, sc, sf, out);
    }
}

// Round 19
// 47.398 us; speedup vs baseline: 1.4374x; 1.1631x over previous
//
#include <hip/hip_runtime.h>
#include <hip/hip_bf16.h>
#include <stdint.h>

#define BB    4
#define NQ    8192
#define NS    4096
#define FDIM  256
#define KNN   8
#define NT    512                // 8 waves; wave w owns tiles [16w,16w+16)
#define QPB   32                 // queries per block (one 32-col MFMA B set)
#define CAP   128                // candidate capacity (E=32, sigma~10 -> ~10 sigma)
#define MARGIN 0.0035f           // > 2x bf16-split error bound (~1.1e-3)
#define TPW   16                 // tiles per wave
#define SAMPT 4                  // sampled tiles per wave (1024 pooled samples)

typedef unsigned long long u64;
typedef __attribute__((ext_vector_type(8)))  short bf16x8;   // 8 bf16 (4 VGPR)
typedef __attribute__((ext_vector_type(16))) float f32x16;   // 32x32 C/D

__device__ __forceinline__ float med3(float a, float b, float c) {
    return __builtin_amdgcn_fmed3f(a, b, c);
}
__device__ __forceinline__ unsigned short f2bf(float v) {
    __hip_bfloat16 h = __float2bfloat16(v);
    return *reinterpret_cast<unsigned short*>(&h);
}
__device__ __forceinline__ float bf2f(unsigned short u) {
    __hip_bfloat16 h;
    *reinterpret_cast<unsigned short*>(&h) = u;
    return __bfloat162float(h);
}

// ---------------- d_ws layout ----------------
// tbl  : [NS][16] bf16 @ 0       (128 KB)  K=16 vectors (11 slots used)
// tblf : [NS] float4  @ 131072   (64 KB)   (-2x,-2y,-2z,s^2) f32 for refine
#define WS_TBLF  131072
#define WS_NEED  196608

// ============ build: bf16 K-vector table + f32 refine table ============
// k: 0:s2_hi 1:s2_lo 2:mx_hi 3:mx_lo 4:mx_hi 5:my_hi 6:my_lo 7:my_hi
//    8:mz_hi 9:mz_lo 10:mz_hi 11..15:0        (m* = -2*coord)
__global__ __launch_bounds__(256) void build_tbl(const float* __restrict__ sc,
                                                 unsigned short* __restrict__ tbl,
                                                 float4* __restrict__ tblf) {
    const int s = blockIdx.x * 256 + threadIdx.x;
    if (s >= NS) return;
    const float sx = sc[3*s], sy = sc[3*s+1], sz = sc[3*s+2];
    const float s2 = __fmaf_rn(sx, sx, __fmaf_rn(sy, sy, __fmul_rn(sz, sz)));
    const float mx = -2.0f*sx, my = -2.0f*sy, mz = -2.0f*sz;
    unsigned short e[16];
    #pragma unroll
    for (int j = 0; j < 16; ++j) e[j] = 0;
    unsigned short h, l;
    h = f2bf(s2); l = f2bf(s2 - bf2f(h)); e[0] = h; e[1] = l;
    h = f2bf(mx); l = f2bf(mx - bf2f(h)); e[2] = h; e[3] = l; e[4]  = h;
    h = f2bf(my); l = f2bf(my - bf2f(h)); e[5] = h; e[6] = l; e[7]  = h;
    h = f2bf(mz); l = f2bf(mz - bf2f(h)); e[8] = h; e[9] = l; e[10] = h;
    #pragma unroll
    for (int j = 0; j < 16; ++j) tbl[s * 16 + j] = e[j];
    tblf[s] = make_float4(mx, my, mz, s2);
}

// ===== main: pooled-sample threshold -> 32x32 MFMA sweep -> parallel exact refine ====
__global__ __launch_bounds__(NT, 8) void knn_mfma(
    const float* __restrict__ qc, const float* __restrict__ sf,
    const unsigned short* __restrict__ tbl, const float4* __restrict__ tblf,
    float* __restrict__ out)
{
    __shared__ unsigned short s_qvec[QPB][16];   // query K-vectors (1 KB)
    __shared__ float4 s_q[QPB];                  // qx,qy,qz,q2 (f32, refine)
    __shared__ float  s_samp[8][8][QPB + 1];     // per-lane top-4s; padded reads
    __shared__ float  s_thrq[QPB];               // pooled threshold (+MARGIN)
    __shared__ int    s_cnt[QPB];
    __shared__ int    s_cand[QPB][CAP];          // 16 KB
    __shared__ int    s_idx[QPB][KNN];
    __shared__ float  s_w[QPB][KNN];

    const int tid = threadIdx.x;

    // XCD swizzle: batch b -> XCD pair {2b,2b+1}; bijective over 1024 blocks.
    const int p   = blockIdx.x;
    const int b   = (p >> 1) & 3;
    const int sub = ((p >> 3) << 1) | (p & 1);   // 0..255
    const int q0  = b * NQ + sub * QPB;

    // ---- stage query K-vectors + f32 coords ----
    if (tid < QPB) {
        const float* qp = qc + (size_t)(q0 + tid) * 3;
        const float qx = qp[0], qy = qp[1], qz = qp[2];
        const float q2 = __fmaf_rn(qx, qx, __fmaf_rn(qy, qy, __fmul_rn(qz, qz)));
        s_q[tid] = make_float4(qx, qy, qz, q2);
        #pragma unroll
        for (int j = 11; j < 16; ++j) s_qvec[tid][j] = 0;
        const unsigned short one = f2bf(1.0f);
        unsigned short h, l;
        s_qvec[tid][0] = one; s_qvec[tid][1] = one;
        h = f2bf(qx); l = f2bf(qx - bf2f(h));
        s_qvec[tid][2] = h; s_qvec[tid][3] = h; s_qvec[tid][4]  = l;
        h = f2bf(qy); l = f2bf(qy - bf2f(h));
        s_qvec[tid][5] = h; s_qvec[tid][6] = h; s_qvec[tid][7]  = l;
        h = f2bf(qz); l = f2bf(qz - bf2f(h));
        s_qvec[tid][8] = h; s_qvec[tid][9] = h; s_qvec[tid][10] = l;
        s_cnt[tid] = 0;
    }
    __syncthreads();

    const int wid  = tid >> 6;        // wave 0..7 -> tiles [wid*16, wid*16+16)
    const int lane = tid & 63;
    const int ln31 = lane & 31;       // A row within tile / B query col
    const int kc   = lane >> 5;       // k-chunk 0..1 (A/B k = 8*kc + j)
    const int t0   = wid * TPW;

    // B fragment: col = lane&31 (query), k = 8*(lane>>5)+j  [r13-verified]
    const bf16x8 bfrag = *reinterpret_cast<const bf16x8*>(&s_qvec[ln31][kc * 8]);
    const f32x16 zero = {};

    // A fragment source: row = lane&31 (sensor in tile), k = 8*(lane>>5)+j
    const unsigned short* abase = tbl + ((size_t)ln31 * 16 + kc * 8);

    // ---- pass S: per-lane TOP-4 over 4 sampled tiles (64 values/lane).
    // Recording only top-4/lane can only RAISE the pooled 8th (safe over-
    // threshold; P(lane holds >=5 of pooled top-8) ~ 1e-5). 5 ops/sample. ----
    float kd0 = 3.4e38f, kd1 = 3.4e38f, kd2 = 3.4e38f, kd3 = 3.4e38f;

    __builtin_amdgcn_s_setprio(1);
    #pragma unroll
    for (int ts = 0; ts < SAMPT; ++ts) {
        const int t = t0 + ts * (TPW / SAMPT);
        const bf16x8 a = *reinterpret_cast<const bf16x8*>(abase + (size_t)t * 512);
        const f32x16 d = __builtin_amdgcn_mfma_f32_32x32x16_bf16(a, bfrag, zero, 0, 0, 0);
        #pragma unroll
        for (int r = 0; r < 16; ++r) {
            const float x = d[r];
            const float nk0 = fminf(kd0, x);
            kd3 = med3(kd2, kd3, x);
            kd2 = med3(kd1, kd2, x);
            kd1 = med3(kd0, kd1, x);
            kd0 = nk0;
        }
    }
    __builtin_amdgcn_s_setprio(0);

    // ---- prefetch pass-C tile 0 (read-only table; legal across barriers) ----
    bf16x8 aC = *reinterpret_cast<const bf16x8*>(abase + (size_t)t0 * 512);

    // ---- record: each lane writes its sorted top-4 (slot = kc*4+j), stride-1 ----
    s_samp[wid][kc * 4 + 0][ln31] = kd0;
    s_samp[wid][kc * 4 + 1][ln31] = kd1;
    s_samp[wid][kc * 4 + 2][ln31] = kd2;
    s_samp[wid][kc * 4 + 3][ln31] = kd3;
    __syncthreads();

    // ---- parallel pool: subgroup (wid,sg) pools query qr = wid*4+sg ----
    // 64 recorded values; lane li holds 4 sorted; 8-round 16-lane pop-tournament
    // -> pooled sample-8th (tie over-pop only raises thr; refine is exact anyway).
    {
        const int sg = lane >> 4;
        const int li = lane & 15;
        const int qr = wid * 4 + sg;
        const int v0 = li * 4;
        const float x0 = s_samp[(v0+0) >> 3][(v0+0) & 7][qr];
        const float x1 = s_samp[(v0+1) >> 3][(v0+1) & 7][qr];
        const float x2 = s_samp[(v0+2) >> 3][(v0+2) & 7][qr];
        const float x3 = s_samp[(v0+3) >> 3][(v0+3) & 7][qr];
        // sort-4 network (ascending)
        const float a0 = fminf(x0, x1), a1 = fmaxf(x0, x1);
        const float a2 = fminf(x2, x3), a3 = fmaxf(x2, x3);
        const float b0 = fminf(a0, a2), b2 = fmaxf(a0, a2);
        const float b1 = fminf(a1, a3), b3 = fmaxf(a1, a3);
        float l0 = b0, l1 = fminf(b1, b2), l2 = fmaxf(b1, b2), l3 = b3;
        float m = 3.4e38f;
        #pragma unroll
        for (int r = 0; r < KNN; ++r) {
            m = l0;
            m = fminf(m, __shfl_xor(m, 1, 64));
            m = fminf(m, __shfl_xor(m, 2, 64));
            m = fminf(m, __shfl_xor(m, 4, 64));
            m = fminf(m, __shfl_xor(m, 8, 64));
            const bool pop = (l0 == m);
            l0 = pop ? l1 : l0;
            l1 = pop ? l2 : l1;
            l2 = pop ? l3 : l2;
            l3 = pop ? 3.4e38f : l3;
        }
        if (li == 0) s_thrq[qr] = m + MARGIN;   // superset threshold (proof as r8)
    }
    __syncthreads();

    const float thr_eff = s_thrq[ln31];

    // ---- pass C: sweep 16 tiles (prefetched A; mask+popc+ffs compaction) ----
    {
        const unsigned short* ap = abase + (size_t)t0 * 512;
        bf16x8 a = aC;
        int sid0 = t0 * 32 + 4 * kc;     // + (r&3) + 8*(r>>2) per element
        __builtin_amdgcn_s_setprio(1);
        #pragma unroll 4
        for (int tt = 0; tt < TPW; ++tt) {
            bf16x8 an = a;
            if (tt + 1 < TPW) {
                ap += 512;
                an = *reinterpret_cast<const bf16x8*>(ap);
            }
            const f32x16 d = __builtin_amdgcn_mfma_f32_32x32x16_bf16(a, bfrag, zero, 0, 0, 0);
            unsigned m = 0;
            #pragma unroll
            for (int r = 0; r < 16; ++r) m |= (d[r] <= thr_eff) ? (1u << r) : 0u;
            if (m) {
                int pos = atomicAdd(&s_cnt[ln31], __popc(m));
                while (m) {                      // iterations = per-lane hits (~1-3)
                    const int r = __ffs(m) - 1;
                    m &= m - 1;
                    if (pos < CAP) s_cand[ln31][pos] = sid0 + (r & 3) + 8 * (r >> 2);
                    ++pos;
                }
            }
            a = an;
            sid0 += 32;
        }
        __builtin_amdgcn_s_setprio(0);
    }
    __syncthreads();

    // ---- parallel exact refine: wave wid -> queries wid*4..+3 ----
    // 16 lanes per query split candidates; per-lane sorted u64 top-8;
    // 16-lane u64 pop-tournament -> exact top-8 (keys unique -> one pop).
    {
        const int sg = lane >> 4;            // subgroup 0..3
        const int li = lane & 15;            // lane within subgroup
        const int qr = wid * 4 + sg;         // query refined by this subgroup (0..31)
        const int cnt0 = s_cnt[qr];
        const float qx = s_q[qr].x, qy = s_q[qr].y, qz = s_q[qr].z, q2 = s_q[qr].w;

        u64 kb[KNN];
        #pragma unroll
        for (int j = 0; j < KNN; ++j) kb[j] = ~0ull;

        if (cnt0 <= CAP) {
            int i = li;
            int sid_cur = (i < cnt0) ? s_cand[qr][i] : -1;
            while (sid_cur >= 0) {
                const float4 m = tblf[sid_cur];         // issue load
                const int i_nxt = i + 16;
                const int sid_nxt = (i_nxt < cnt0) ? s_cand[qr][i_nxt] : -1;  // prefetch
                const float x  = __fmaf_rn(qx, m.x,
                                 __fmaf_rn(qy, m.y, __fmaf_rn(qz, m.z, m.w)));
                const float d2 = fmaxf(__fadd_rn(x, q2), 0.0f);
                u64 cur = ((u64)__float_as_uint(d2) << 32) | (unsigned)sid_cur;
                #pragma unroll
                for (int j = 0; j < KNN; ++j) {
                    const u64 lo = kb[j] < cur ? kb[j] : cur;
                    const u64 hi = kb[j] < cur ? cur : kb[j];
                    kb[j] = lo; cur = hi;
                }
                i = i_nxt;
                sid_cur = sid_nxt;
            }
        } else {
            // safety net (~10 sigma): exact full scan, split over 16 lanes
            for (int sid = li; sid < NS; sid += 16) {
                const float4 m = tblf[sid];
                const float x  = __fmaf_rn(qx, m.x,
                                 __fmaf_rn(qy, m.y, __fmaf_rn(qz, m.z, m.w)));
                const float d2 = fmaxf(__fadd_rn(x, q2), 0.0f);
                u64 cur = ((u64)__float_as_uint(d2) << 32) | (unsigned)sid;
                #pragma unroll
                for (int j = 0; j < KNN; ++j) {
                    const u64 lo = kb[j] < cur ? kb[j] : cur;
                    const u64 hi = kb[j] < cur ? cur : kb[j];
                    kb[j] = lo; cur = hi;
                }
            }
        }

        u64 sel = ~0ull;
        #pragma unroll
        for (int r = 0; r < KNN; ++r) {
            u64 v = kb[0];
            #pragma unroll
            for (int m = 1; m <= 8; m <<= 1) {
                const u64 o = __shfl_xor(v, m, 64);   // stays within 16-lane group
                v = o < v ? o : v;
            }
            const bool pop = (kb[0] == v);
            #pragma unroll
            for (int j = 0; j < KNN - 1; ++j) kb[j] = pop ? kb[j+1] : kb[j];
            kb[KNN-1] = pop ? ~0ull : kb[KNN-1];
            if (li == r) sel = v;
        }

        // weights on lanes 0..7 of each subgroup (xor 1,2,4 stays within 0..7)
        const float d2v = __uint_as_float((unsigned)(sel >> 32));
        const int   idx = (int)(unsigned)(sel & 0xFFFFFFFFu);
        const float w   = 1.0f / (sqrtf(d2v) + 1e-8f);
        float ws = w;
        ws += __shfl_xor(ws, 1, 64);
        ws += __shfl_xor(ws, 2, 64);
        ws += __shfl_xor(ws, 4, 64);
        if (li < KNN) {
            s_idx[qr][li] = idx;
            s_w[qr][li]   = w / ws;
        }
    }
    __syncthreads();

    // ---- gather: wave wid -> queries wid*4..+3; 64 lanes x float4 ----
    const float* fb = sf + (size_t)b * NS * FDIM;
    #pragma unroll 4
    for (int jq = 0; jq < QPB / 8; ++jq) {
        const int ql = wid * (QPB / 8) + jq;
        float4 acc = {0.f, 0.f, 0.f, 0.f};
        #pragma unroll
        for (int kk = 0; kk < KNN; ++kk) {
            const int   sid = s_idx[ql][kk];
            const float wk  = s_w[ql][kk];
            const float4 v = ((const float4*)(fb + (size_t)sid * FDIM))[lane];
            acc.x += wk * v.x; acc.y += wk * v.y;
            acc.z += wk * v.z; acc.w += wk * v.w;
        }
        ((float4*)(out + (size_t)(q0 + ql) * FDIM))[lane] = acc;
    }
}

// ================= fallback (round-6 kernel) if workspace too small =================
#define FG    16
#define FQL   2
#define FNT   512
#define FGRP  (FNT / FG)
#define FQPB  (FGRP * FQL)
#define FSCAN (NS / FG)
#define FCAP  16

#define FKEYX(m, qq) __fmaf_rn(fqx[qq], (m).x, \
                     __fmaf_rn(fqy[qq], (m).y, \
                     __fmaf_rn(fqz[qq], (m).z, (m).w)))

__global__ __launch_bounds__(FNT, 4) void idw_fallback(
    const float* __restrict__ qc, const float* __restrict__ sc,
    const float* __restrict__ sf, float* __restrict__ out)
{
    __shared__ float4 s_m[NS];
    __shared__ u64    s_items[FQPB * FCAP];
    __shared__ int    s_cnt[FQPB];
    __shared__ int    s_idx[FQPB * KNN];
    __shared__ float  s_w[FQPB * KNN];

    const int tid = threadIdx.x;
    const int p   = blockIdx.x;
    const int b   = (p >> 1) & 3;
    const int sub = ((p >> 3) << 1) | (p & 1);
    const int q0  = b * NQ + sub * FQPB;

    for (int s = tid; s < NS; s += FNT) {
        const float sx = sc[3*s+0], sy = sc[3*s+1], sz = sc[3*s+2];
        const float s2 = __fmaf_rn(sx, sx, __fmaf_rn(sy, sy, __fmul_rn(sz, sz)));
        s_m[s] = make_float4(-2.0f*sx, -2.0f*sy, -2.0f*sz, s2);
    }
    if (tid < FQPB) s_cnt[tid] = 0;
    __syncthreads();

    const int g = tid >> 4, l = tid & 15;
    float fqx[FQL], fqy[FQL], fqz[FQL], fq2[FQL];
    #pragma unroll
    for (int qq = 0; qq < FQL; ++qq) {
        const float* qp = qc + (size_t)(q0 + g * FQL + qq) * 3;
        fqx[qq] = qp[0]; fqy[qq] = qp[1]; fqz[qq] = qp[2];
        fq2[qq] = __fmaf_rn(fqx[qq], fqx[qq],
                  __fmaf_rn(fqy[qq], fqy[qq], __fmul_rn(fqz[qq], fqz[qq])));
    }

    float kd[FQL][KNN];
    #pragma unroll
    for (int qq = 0; qq < FQL; ++qq)
        #pragma unroll
        for (int j = 0; j < KNN; ++j) kd[qq][j] = 3.4e38f;

    #pragma unroll 2
    for (int t = 0; t < FSCAN; ++t) {
        const float4 m = s_m[t * FG + l];
        #pragma unroll
        for (int qq = 0; qq < FQL; ++qq) {
            const float x = FKEYX(m, qq);
            const float nk0 = fminf(kd[qq][0], x);
            #pragma unroll
            for (int j = KNN - 1; j >= 1; --j)
                kd[qq][j] = med3(kd[qq][j-1], kd[qq][j], x);
            kd[qq][0] = nk0;
        }
    }

    float thr[FQL];
    #pragma unroll
    for (int qq = 0; qq < FQL; ++qq) {
        float thv = 3.4e38f;
        #pragma unroll
        for (int r = 0; r < KNN; ++r) {
            float m = kd[qq][0];
            m = fminf(m, __shfl_xor(m, 1, 64));
            m = fminf(m, __shfl_xor(m, 2, 64));
            m = fminf(m, __shfl_xor(m, 4, 64));
            m = fminf(m, __shfl_xor(m, 8, 64));
            const bool pop = (kd[qq][0] == m);
            #pragma unroll
            for (int j = 0; j < KNN - 1; ++j) kd[qq][j] = pop ? kd[qq][j+1] : kd[qq][j];
            kd[qq][KNN-1] = pop ? 3.4e38f : kd[qq][KNN-1];
            thv = m;
        }
        thr[qq] = thv;
    }

    #pragma unroll 2
    for (int t = 0; t < FSCAN; ++t) {
        const int s = t * FG + l;
        const float4 m = s_m[s];
        #pragma unroll
        for (int qq = 0; qq < FQL; ++qq) {
            const float x = FKEYX(m, qq);
            if (x <= thr[qq]) {
                const float dc = fmaxf(__fadd_rn(x, fq2[qq]), 0.0f);
                const u64 key = ((u64)__float_as_uint(dc) << 32) | (unsigned)s;
                const int qid = g * FQL + qq;
                const int pos = atomicAdd(&s_cnt[qid], 1);
                if (pos < FCAP) s_items[qid * FCAP + pos] = key;
            }
        }
    }
    __syncthreads();

    if (l < FQL) {
        const int qid = g * FQL + l;
        int cnt = s_cnt[qid];
        if (cnt > KNN) {
            cnt = cnt < FCAP ? cnt : FCAP;
            u64 best[KNN];
            #pragma unroll
            for (int j = 0; j < KNN; ++j) best[j] = ~0ull;
            for (int i = 0; i < cnt; ++i) {
                u64 cur = s_items[qid * FCAP + i];
                #pragma unroll
                for (int j = 0; j < KNN; ++j) {
                    const u64 lo = best[j] < cur ? best[j] : cur;
                    const u64 hi = best[j] < cur ? cur : best[j];
                    best[j] = lo; cur = hi;
                }
            }
            #pragma unroll
            for (int j = 0; j < KNN; ++j) s_items[qid * FCAP + j] = best[j];
        }
    }
    __syncthreads();

    {
        const int qq  = l >> 3;
        const int k   = l & 7;
        const int qid = g * FQL + qq;
        const u64 key = s_items[qid * FCAP + k];
        const float d2v = __uint_as_float((unsigned)(key >> 32));
        const int   idx = (int)(unsigned)(key & 0xFFFFFFFFu);
        const float w   = 1.0f / (sqrtf(d2v) + 1e-8f);
        float ws = w;
        ws += __shfl_xor(ws, 1, 64);
        ws += __shfl_xor(ws, 2, 64);
        ws += __shfl_xor(ws, 4, 64);
        s_idx[qid * KNN + k] = idx;
        s_w  [qid * KNN + k] = w / ws;
    }
    __syncthreads();

    const int wave = tid >> 6, lane = tid & 63;
    const float* fb = sf + (size_t)b * NS * FDIM;
    #pragma unroll 1
    for (int j = 0; j < FQPB / 8; ++j) {
        const int ql = wave * (FQPB / 8) + j;
        float4 acc = {0.f, 0.f, 0.f, 0.f};
        #pragma unroll
        for (int kk = 0; kk < KNN; ++kk) {
            const int   sid = s_idx[ql * KNN + kk];
            const float wk  = s_w  [ql * KNN + kk];
            const float4 v = ((const float4*)(fb + (size_t)sid * FDIM))[lane];
            acc.x += wk * v.x; acc.y += wk * v.y;
            acc.z += wk * v.z; acc.w += wk * v.w;
        }
        ((float4*)(out + (size_t)(q0 + ql) * FDIM))[lane] = acc;
    }
}

extern "C" void kernel_launch(void* const* d_in, const int* in_sizes, int n_in,
                              void* d_out, int out_size, void* d_ws, size_t ws_size,
                              hipStream_t stream) {
    const float* qc = (const float*)d_in[0];   // query_coords  (4,8192,3)
    const float* sc = (const float*)d_in[1];   // sensor_coords (4096,3)
    const float* sf = (const float*)d_in[2];   // sensor_features (4,4096,256)
    float* out = (float*)d_out;                // (4,8192,256)

    if (ws_size >= (size_t)WS_NEED) {
        unsigned short* tbl  = (unsigned short*)d_ws;
        float4*         tblf = (float4*)((char*)d_ws + WS_TBLF);
        build_tbl<<<NS / 256, 256, 0, stream>>>(sc, tbl, tblf);
        knn_mfma<<<(BB * NQ) / QPB, NT, 0, stream>>>(qc, sf, tbl, tblf, out);
    } else {
        idw_fallback<<<(BB * NQ) / FQPB, FNT, 0, stream>>>(qc, sc, sf, out);
    }
}

// Round 20
// 47.058 us; speedup vs baseline: 1.4478x; 1.0072x over previous
//
#include <hip/hip_runtime.h>
#include <hip/hip_bf16.h>
#include <stdint.h>

#define BB    4
#define NQ    8192
#define NS    4096
#define FDIM  256
#define KNN   8
#define NT    512                // 8 waves; wave w owns tiles [16w,16w+16)
#define QPB   32                 // queries per block (one 32-col MFMA B set)
#define CAP   128                // candidate capacity (E=32, sigma~10 -> ~10 sigma)
#define MARGIN 0.0035f           // > 2x bf16-split error bound (~1.1e-3)
#define TPW   16                 // tiles per wave
#define SAMPT 4                  // sampled tiles per wave (1024 pooled samples)

typedef unsigned long long u64;
typedef __attribute__((ext_vector_type(8)))  short bf16x8;   // 8 bf16 (4 VGPR)
typedef __attribute__((ext_vector_type(16))) float f32x16;   // 32x32 C/D

__device__ __forceinline__ float med3(float a, float b, float c) {
    return __builtin_amdgcn_fmed3f(a, b, c);
}
__device__ __forceinline__ unsigned short f2bf(float v) {
    __hip_bfloat16 h = __float2bfloat16(v);
    return *reinterpret_cast<unsigned short*>(&h);
}
__device__ __forceinline__ float bf2f(unsigned short u) {
    __hip_bfloat16 h;
    *reinterpret_cast<unsigned short*>(&h) = u;
    return __bfloat162float(h);
}

// ---------------- d_ws layout ----------------
// tbl  : [NS][16] bf16 @ 0       (128 KB)  K=16 vectors (11 slots used)
// tblf : [NS] float4  @ 131072   (64 KB)   (-2x,-2y,-2z,s^2) f32 for refine
#define WS_TBLF  131072
#define WS_NEED  196608

// ============ build: bf16 K-vector table + f32 refine table ============
// k: 0:s2_hi 1:s2_lo 2:mx_hi 3:mx_lo 4:mx_hi 5:my_hi 6:my_lo 7:my_hi
//    8:mz_hi 9:mz_lo 10:mz_hi 11..15:0        (m* = -2*coord)
__global__ __launch_bounds__(256) void build_tbl(const float* __restrict__ sc,
                                                 unsigned short* __restrict__ tbl,
                                                 float4* __restrict__ tblf) {
    const int s = blockIdx.x * 256 + threadIdx.x;
    if (s >= NS) return;
    const float sx = sc[3*s], sy = sc[3*s+1], sz = sc[3*s+2];
    const float s2 = __fmaf_rn(sx, sx, __fmaf_rn(sy, sy, __fmul_rn(sz, sz)));
    const float mx = -2.0f*sx, my = -2.0f*sy, mz = -2.0f*sz;
    unsigned short e[16];
    #pragma unroll
    for (int j = 0; j < 16; ++j) e[j] = 0;
    unsigned short h, l;
    h = f2bf(s2); l = f2bf(s2 - bf2f(h)); e[0] = h; e[1] = l;
    h = f2bf(mx); l = f2bf(mx - bf2f(h)); e[2] = h; e[3] = l; e[4]  = h;
    h = f2bf(my); l = f2bf(my - bf2f(h)); e[5] = h; e[6] = l; e[7]  = h;
    h = f2bf(mz); l = f2bf(mz - bf2f(h)); e[8] = h; e[9] = l; e[10] = h;
    #pragma unroll
    for (int j = 0; j < 16; ++j) tbl[s * 16 + j] = e[j];
    tblf[s] = make_float4(mx, my, mz, s2);
}

// ===== main: pooled-sample threshold -> 32x32 MFMA sweep -> parallel exact refine ====
__global__ __launch_bounds__(NT, 8) void knn_mfma(
    const float* __restrict__ qc, const float* __restrict__ sf,
    const unsigned short* __restrict__ tbl, const float4* __restrict__ tblf,
    float* __restrict__ out)
{
    __shared__ unsigned short s_qvec[QPB][16];   // query K-vectors (1 KB)
    __shared__ float4 s_q[QPB];                  // qx,qy,qz,q2 (f32, refine)
    __shared__ float  s_samp[8][8][QPB + 1];     // per-lane top-4s; padded reads
    __shared__ float  s_thrq[QPB];               // pooled threshold (+MARGIN)
    __shared__ int    s_cnt[QPB];
    __shared__ int    s_cand[QPB][CAP];          // 16 KB
    __shared__ int    s_idx[QPB][KNN];
    __shared__ float  s_w[QPB][KNN];

    const int tid = threadIdx.x;

    // XCD swizzle: batch b -> XCD pair {2b,2b+1}; bijective over 1024 blocks.
    const int p   = blockIdx.x;
    const int b   = (p >> 1) & 3;
    const int sub = ((p >> 3) << 1) | (p & 1);   // 0..255
    const int q0  = b * NQ + sub * QPB;

    // ---- stage query K-vectors + f32 coords ----
    if (tid < QPB) {
        const float* qp = qc + (size_t)(q0 + tid) * 3;
        const float qx = qp[0], qy = qp[1], qz = qp[2];
        const float q2 = __fmaf_rn(qx, qx, __fmaf_rn(qy, qy, __fmul_rn(qz, qz)));
        s_q[tid] = make_float4(qx, qy, qz, q2);
        #pragma unroll
        for (int j = 11; j < 16; ++j) s_qvec[tid][j] = 0;
        const unsigned short one = f2bf(1.0f);
        unsigned short h, l;
        s_qvec[tid][0] = one; s_qvec[tid][1] = one;
        h = f2bf(qx); l = f2bf(qx - bf2f(h));
        s_qvec[tid][2] = h; s_qvec[tid][3] = h; s_qvec[tid][4]  = l;
        h = f2bf(qy); l = f2bf(qy - bf2f(h));
        s_qvec[tid][5] = h; s_qvec[tid][6] = h; s_qvec[tid][7]  = l;
        h = f2bf(qz); l = f2bf(qz - bf2f(h));
        s_qvec[tid][8] = h; s_qvec[tid][9] = h; s_qvec[tid][10] = l;
        s_cnt[tid] = 0;
    }
    __syncthreads();

    const int wid  = tid >> 6;        // wave 0..7 -> tiles [wid*16, wid*16+16)
    const int lane = tid & 63;
    const int ln31 = lane & 31;       // A row within tile / B query col
    const int kc   = lane >> 5;       // k-chunk 0..1 (A/B k = 8*kc + j)
    const int t0   = wid * TPW;

    // B fragment: col = lane&31 (query), k = 8*(lane>>5)+j  [r13-verified]
    const bf16x8 bfrag = *reinterpret_cast<const bf16x8*>(&s_qvec[ln31][kc * 8]);
    const f32x16 zero = {};

    // A fragment source: row = lane&31 (sensor in tile), k = 8*(lane>>5)+j
    const unsigned short* abase = tbl + ((size_t)ln31 * 16 + kc * 8);

    // ---- pass S: per-lane TOP-4 over 4 sampled tiles (64 values/lane).
    // Recording only top-4/lane can only RAISE the pooled 8th (safe over-
    // threshold; P(lane holds >=5 of pooled top-8) ~ 1e-5). 5 ops/sample. ----
    float kd0 = 3.4e38f, kd1 = 3.4e38f, kd2 = 3.4e38f, kd3 = 3.4e38f;

    __builtin_amdgcn_s_setprio(1);
    #pragma unroll
    for (int ts = 0; ts < SAMPT; ++ts) {
        const int t = t0 + ts * (TPW / SAMPT);
        const bf16x8 a = *reinterpret_cast<const bf16x8*>(abase + (size_t)t * 512);
        const f32x16 d = __builtin_amdgcn_mfma_f32_32x32x16_bf16(a, bfrag, zero, 0, 0, 0);
        #pragma unroll
        for (int r = 0; r < 16; ++r) {
            const float x = d[r];
            const float nk0 = fminf(kd0, x);
            kd3 = med3(kd2, kd3, x);
            kd2 = med3(kd1, kd2, x);
            kd1 = med3(kd0, kd1, x);
            kd0 = nk0;
        }
    }
    __builtin_amdgcn_s_setprio(0);

    // ---- prefetch pass-C tile 0 (read-only table; legal across barriers) ----
    bf16x8 aC = *reinterpret_cast<const bf16x8*>(abase + (size_t)t0 * 512);

    // ---- record: each lane writes its sorted top-4 (slot = kc*4+j), stride-1 ----
    s_samp[wid][kc * 4 + 0][ln31] = kd0;
    s_samp[wid][kc * 4 + 1][ln31] = kd1;
    s_samp[wid][kc * 4 + 2][ln31] = kd2;
    s_samp[wid][kc * 4 + 3][ln31] = kd3;
    __syncthreads();

    // ---- parallel pool: subgroup (wid,sg) pools query qr = wid*4+sg ----
    // 64 recorded values; lane li holds 4 sorted; 8-round 16-lane pop-tournament
    // -> pooled sample-8th (tie over-pop only raises thr; refine is exact anyway).
    {
        const int sg = lane >> 4;
        const int li = lane & 15;
        const int qr = wid * 4 + sg;
        const int v0 = li * 4;
        const float x0 = s_samp[(v0+0) >> 3][(v0+0) & 7][qr];
        const float x1 = s_samp[(v0+1) >> 3][(v0+1) & 7][qr];
        const float x2 = s_samp[(v0+2) >> 3][(v0+2) & 7][qr];
        const float x3 = s_samp[(v0+3) >> 3][(v0+3) & 7][qr];
        // sort-4 network (ascending)
        const float a0 = fminf(x0, x1), a1 = fmaxf(x0, x1);
        const float a2 = fminf(x2, x3), a3 = fmaxf(x2, x3);
        const float b0 = fminf(a0, a2), b2 = fmaxf(a0, a2);
        const float b1 = fminf(a1, a3), b3 = fmaxf(a1, a3);
        float l0 = b0, l1 = fminf(b1, b2), l2 = fmaxf(b1, b2), l3 = b3;
        float m = 3.4e38f;
        #pragma unroll
        for (int r = 0; r < KNN; ++r) {
            m = l0;
            m = fminf(m, __shfl_xor(m, 1, 64));
            m = fminf(m, __shfl_xor(m, 2, 64));
            m = fminf(m, __shfl_xor(m, 4, 64));
            m = fminf(m, __shfl_xor(m, 8, 64));
            const bool pop = (l0 == m);
            l0 = pop ? l1 : l0;
            l1 = pop ? l2 : l1;
            l2 = pop ? l3 : l2;
            l3 = pop ? 3.4e38f : l3;
        }
        if (li == 0) s_thrq[qr] = m + MARGIN;   // superset threshold (proof as r8)
    }
    __syncthreads();

    const float thr_eff = s_thrq[ln31];

    // ---- pass C: sweep 16 tiles. Threshold folded into MFMA C-operand:
    // d'[r] = x - thr (per-lane thr is per-query since C/D cols = ln31).
    // Hit iff d' < 0 (sign bit). Strict < is safe: needed x satisfy
    // x <= pooled8th + 1.1e-3 < thr (MARGIN 3.5e-3); the C-fold rounding
    // delta (~1e-6) is absorbed by the 2.4e-3 slack. Refine is exact anyway. ----
    {
        f32x16 cneg;
        #pragma unroll
        for (int r = 0; r < 16; ++r) cneg[r] = -thr_eff;

        const unsigned short* ap = abase + (size_t)t0 * 512;
        bf16x8 a = aC;
        int sid0 = t0 * 32 + 4 * kc;     // + (r&3) + 8*(r>>2) per element
        __builtin_amdgcn_s_setprio(1);
        #pragma unroll 4
        for (int tt = 0; tt < TPW; ++tt) {
            bf16x8 an = a;
            if (tt + 1 < TPW) {
                ap += 512;
                an = *reinterpret_cast<const bf16x8*>(ap);
            }
            const f32x16 d = __builtin_amdgcn_mfma_f32_32x32x16_bf16(a, bfrag, cneg, 0, 0, 0);
            unsigned m = 0;
            #pragma unroll
            for (int r = 0; r < 16; ++r)
                m |= (__float_as_uint(d[r]) >> 31) << r;   // sign bit = hit
            if (m) {
                int pos = atomicAdd(&s_cnt[ln31], __popc(m));
                while (m) {                      // iterations = per-lane hits (~1-3)
                    const int r = __ffs(m) - 1;
                    m &= m - 1;
                    if (pos < CAP) s_cand[ln31][pos] = sid0 + (r & 3) + 8 * (r >> 2);
                    ++pos;
                }
            }
            a = an;
            sid0 += 32;
        }
        __builtin_amdgcn_s_setprio(0);
    }
    __syncthreads();

    // ---- parallel exact refine: wave wid -> queries wid*4..+3 ----
    // 16 lanes per query split candidates; per-lane sorted u64 top-8;
    // 16-lane u64 pop-tournament -> exact top-8 (keys unique -> one pop).
    {
        const int sg = lane >> 4;            // subgroup 0..3
        const int li = lane & 15;            // lane within subgroup
        const int qr = wid * 4 + sg;         // query refined by this subgroup (0..31)
        const int cnt0 = s_cnt[qr];
        const float qx = s_q[qr].x, qy = s_q[qr].y, qz = s_q[qr].z, q2 = s_q[qr].w;

        u64 kb[KNN];
        #pragma unroll
        for (int j = 0; j < KNN; ++j) kb[j] = ~0ull;

        if (cnt0 <= CAP) {
            int i = li;
            int sid_cur = (i < cnt0) ? s_cand[qr][i] : -1;
            while (sid_cur >= 0) {
                const float4 m = tblf[sid_cur];         // issue load
                const int i_nxt = i + 16;
                const int sid_nxt = (i_nxt < cnt0) ? s_cand[qr][i_nxt] : -1;  // prefetch
                const float x  = __fmaf_rn(qx, m.x,
                                 __fmaf_rn(qy, m.y, __fmaf_rn(qz, m.z, m.w)));
                const float d2 = fmaxf(__fadd_rn(x, q2), 0.0f);
                u64 cur = ((u64)__float_as_uint(d2) << 32) | (unsigned)sid_cur;
                #pragma unroll
                for (int j = 0; j < KNN; ++j) {
                    const u64 lo = kb[j] < cur ? kb[j] : cur;
                    const u64 hi = kb[j] < cur ? cur : kb[j];
                    kb[j] = lo; cur = hi;
                }
                i = i_nxt;
                sid_cur = sid_nxt;
            }
        } else {
            // safety net (~10 sigma): exact full scan, split over 16 lanes
            for (int sid = li; sid < NS; sid += 16) {
                const float4 m = tblf[sid];
                const float x  = __fmaf_rn(qx, m.x,
                                 __fmaf_rn(qy, m.y, __fmaf_rn(qz, m.z, m.w)));
                const float d2 = fmaxf(__fadd_rn(x, q2), 0.0f);
                u64 cur = ((u64)__float_as_uint(d2) << 32) | (unsigned)sid;
                #pragma unroll
                for (int j = 0; j < KNN; ++j) {
                    const u64 lo = kb[j] < cur ? kb[j] : cur;
                    const u64 hi = kb[j] < cur ? cur : kb[j];
                    kb[j] = lo; cur = hi;
                }
            }
        }

        u64 sel = ~0ull;
        #pragma unroll
        for (int r = 0; r < KNN; ++r) {
            u64 v = kb[0];
            #pragma unroll
            for (int m = 1; m <= 8; m <<= 1) {
                const u64 o = __shfl_xor(v, m, 64);   // stays within 16-lane group
                v = o < v ? o : v;
            }
            const bool pop = (kb[0] == v);
            #pragma unroll
            for (int j = 0; j < KNN - 1; ++j) kb[j] = pop ? kb[j+1] : kb[j];
            kb[KNN-1] = pop ? ~0ull : kb[KNN-1];
            if (li == r) sel = v;
        }

        // weights on lanes 0..7 of each subgroup (xor 1,2,4 stays within 0..7)
        const float d2v = __uint_as_float((unsigned)(sel >> 32));
        const int   idx = (int)(unsigned)(sel & 0xFFFFFFFFu);
        const float w   = 1.0f / (sqrtf(d2v) + 1e-8f);
        float ws = w;
        ws += __shfl_xor(ws, 1, 64);
        ws += __shfl_xor(ws, 2, 64);
        ws += __shfl_xor(ws, 4, 64);
        if (li < KNN) {
            s_idx[qr][li] = idx;
            s_w[qr][li]   = w / ws;
        }
    }
    __syncthreads();

    // ---- gather: wave wid -> queries wid*4..+3; 64 lanes x float4 ----
    const float* fb = sf + (size_t)b * NS * FDIM;
    #pragma unroll 4
    for (int jq = 0; jq < QPB / 8; ++jq) {
        const int ql = wid * (QPB / 8) + jq;
        float4 acc = {0.f, 0.f, 0.f, 0.f};
        #pragma unroll
        for (int kk = 0; kk < KNN; ++kk) {
            const int   sid = s_idx[ql][kk];
            const float wk  = s_w[ql][kk];
            const float4 v = ((const float4*)(fb + (size_t)sid * FDIM))[lane];
            acc.x += wk * v.x; acc.y += wk * v.y;
            acc.z += wk * v.z; acc.w += wk * v.w;
        }
        ((float4*)(out + (size_t)(q0 + ql) * FDIM))[lane] = acc;
    }
}

// ================= fallback (round-6 kernel) if workspace too small =================
#define FG    16
#define FQL   2
#define FNT   512
#define FGRP  (FNT / FG)
#define FQPB  (FGRP * FQL)
#define FSCAN (NS / FG)
#define FCAP  16

#define FKEYX(m, qq) __fmaf_rn(fqx[qq], (m).x, \
                     __fmaf_rn(fqy[qq], (m).y, \
                     __fmaf_rn(fqz[qq], (m).z, (m).w)))

__global__ __launch_bounds__(FNT, 4) void idw_fallback(
    const float* __restrict__ qc, const float* __restrict__ sc,
    const float* __restrict__ sf, float* __restrict__ out)
{
    __shared__ float4 s_m[NS];
    __shared__ u64    s_items[FQPB * FCAP];
    __shared__ int    s_cnt[FQPB];
    __shared__ int    s_idx[FQPB * KNN];
    __shared__ float  s_w[FQPB * KNN];

    const int tid = threadIdx.x;
    const int p   = blockIdx.x;
    const int b   = (p >> 1) & 3;
    const int sub = ((p >> 3) << 1) | (p & 1);
    const int q0  = b * NQ + sub * FQPB;

    for (int s = tid; s < NS; s += FNT) {
        const float sx = sc[3*s+0], sy = sc[3*s+1], sz = sc[3*s+2];
        const float s2 = __fmaf_rn(sx, sx, __fmaf_rn(sy, sy, __fmul_rn(sz, sz)));
        s_m[s] = make_float4(-2.0f*sx, -2.0f*sy, -2.0f*sz, s2);
    }
    if (tid < FQPB) s_cnt[tid] = 0;
    __syncthreads();

    const int g = tid >> 4, l = tid & 15;
    float fqx[FQL], fqy[FQL], fqz[FQL], fq2[FQL];
    #pragma unroll
    for (int qq = 0; qq < FQL; ++qq) {
        const float* qp = qc + (size_t)(q0 + g * FQL + qq) * 3;
        fqx[qq] = qp[0]; fqy[qq] = qp[1]; fqz[qq] = qp[2];
        fq2[qq] = __fmaf_rn(fqx[qq], fqx[qq],
                  __fmaf_rn(fqy[qq], fqy[qq], __fmul_rn(fqz[qq], fqz[qq])));
    }

    float kd[FQL][KNN];
    #pragma unroll
    for (int qq = 0; qq < FQL; ++qq)
        #pragma unroll
        for (int j = 0; j < KNN; ++j) kd[qq][j] = 3.4e38f;

    #pragma unroll 2
    for (int t = 0; t < FSCAN; ++t) {
        const float4 m = s_m[t * FG + l];
        #pragma unroll
        for (int qq = 0; qq < FQL; ++qq) {
            const float x = FKEYX(m, qq);
            const float nk0 = fminf(kd[qq][0], x);
            #pragma unroll
            for (int j = KNN - 1; j >= 1; --j)
                kd[qq][j] = med3(kd[qq][j-1], kd[qq][j], x);
            kd[qq][0] = nk0;
        }
    }

    float thr[FQL];
    #pragma unroll
    for (int qq = 0; qq < FQL; ++qq) {
        float thv = 3.4e38f;
        #pragma unroll
        for (int r = 0; r < KNN; ++r) {
            float m = kd[qq][0];
            m = fminf(m, __shfl_xor(m, 1, 64));
            m = fminf(m, __shfl_xor(m, 2, 64));
            m = fminf(m, __shfl_xor(m, 4, 64));
            m = fminf(m, __shfl_xor(m, 8, 64));
            const bool pop = (kd[qq][0] == m);
            #pragma unroll
            for (int j = 0; j < KNN - 1; ++j) kd[qq][j] = pop ? kd[qq][j+1] : kd[qq][j];
            kd[qq][KNN-1] = pop ? 3.4e38f : kd[qq][KNN-1];
            thv = m;
        }
        thr[qq] = thv;
    }

    #pragma unroll 2
    for (int t = 0; t < FSCAN; ++t) {
        const int s = t * FG + l;
        const float4 m = s_m[s];
        #pragma unroll
        for (int qq = 0; qq < FQL; ++qq) {
            const float x = FKEYX(m, qq);
            if (x <= thr[qq]) {
                const float dc = fmaxf(__fadd_rn(x, fq2[qq]), 0.0f);
                const u64 key = ((u64)__float_as_uint(dc) << 32) | (unsigned)s;
                const int qid = g * FQL + qq;
                const int pos = atomicAdd(&s_cnt[qid], 1);
                if (pos < FCAP) s_items[qid * FCAP + pos] = key;
            }
        }
    }
    __syncthreads();

    if (l < FQL) {
        const int qid = g * FQL + l;
        int cnt = s_cnt[qid];
        if (cnt > KNN) {
            cnt = cnt < FCAP ? cnt : FCAP;
            u64 best[KNN];
            #pragma unroll
            for (int j = 0; j < KNN; ++j) best[j] = ~0ull;
            for (int i = 0; i < cnt; ++i) {
                u64 cur = s_items[qid * FCAP + i];
                #pragma unroll
                for (int j = 0; j < KNN; ++j) {
                    const u64 lo = best[j] < cur ? best[j] : cur;
                    const u64 hi = best[j] < cur ? cur : best[j];
                    best[j] = lo; cur = hi;
                }
            }
            #pragma unroll
            for (int j = 0; j < KNN; ++j) s_items[qid * FCAP + j] = best[j];
        }
    }
    __syncthreads();

    {
        const int qq  = l >> 3;
        const int k   = l & 7;
        const int qid = g * FQL + qq;
        const u64 key = s_items[qid * FCAP + k];
        const float d2v = __uint_as_float((unsigned)(key >> 32));
        const int   idx = (int)(unsigned)(key & 0xFFFFFFFFu);
        const float w   = 1.0f / (sqrtf(d2v) + 1e-8f);
        float ws = w;
        ws += __shfl_xor(ws, 1, 64);
        ws += __shfl_xor(ws, 2, 64);
        ws += __shfl_xor(ws, 4, 64);
        s_idx[qid * KNN + k] = idx;
        s_w  [qid * KNN + k] = w / ws;
    }
    __syncthreads();

    const int wave = tid >> 6, lane = tid & 63;
    const float* fb = sf + (size_t)b * NS * FDIM;
    #pragma unroll 1
    for (int j = 0; j < FQPB / 8; ++j) {
        const int ql = wave * (FQPB / 8) + j;
        float4 acc = {0.f, 0.f, 0.f, 0.f};
        #pragma unroll
        for (int kk = 0; kk < KNN; ++kk) {
            const int   sid = s_idx[ql * KNN + kk];
            const float wk  = s_w  [ql * KNN + kk];
            const float4 v = ((const float4*)(fb + (size_t)sid * FDIM))[lane];
            acc.x += wk * v.x; acc.y += wk * v.y;
            acc.z += wk * v.z; acc.w += wk * v.w;
        }
        ((float4*)(out + (size_t)(q0 + ql) * FDIM))[lane] = acc;
    }
}

extern "C" void kernel_launch(void* const* d_in, const int* in_sizes, int n_in,
                              void* d_out, int out_size, void* d_ws, size_t ws_size,
                              hipStream_t stream) {
    const float* qc = (const float*)d_in[0];   // query_coords  (4,8192,3)
    const float* sc = (const float*)d_in[1];   // sensor_coords (4096,3)
    const float* sf = (const float*)d_in[2];   // sensor_features (4,4096,256)
    float* out = (float*)d_out;                // (4,8192,256)

    if (ws_size >= (size_t)WS_NEED) {
        unsigned short* tbl  = (unsigned short*)d_ws;
        float4*         tblf = (float4*)((char*)d_ws + WS_TBLF);
        build_tbl<<<NS / 256, 256, 0, stream>>>(sc, tbl, tblf);
        knn_mfma<<<(BB * NQ) / QPB, NT, 0, stream>>>(qc, sf, tbl, tblf, out);
    } else {
        idw_fallback<<<(BB * NQ) / FQPB, FNT, 0, stream>>>(qc, sc, sf, out);
    }
}